// Round 8
// baseline (2815.346 us; speedup 1.0000x reference)
//
#include <hip/hip_runtime.h>
#include <math.h>

#define NPTS 4096
#define NBATCH 4
#define NTOT (NBATCH*NPTS)
#define KNN 20

__device__ __forceinline__ float lrelu_f(float h) { return h >= 0.f ? h : 0.2f * h; }

// ---------------- x:(B,6,N) -> xyzT:(B*N,6) ----------------
__global__ __launch_bounds__(256) void k_transpose_in(const float* __restrict__ x, float* __restrict__ xyzT)
{
    int p = blockIdx.x * 256 + threadIdx.x;
    if (p >= NTOT) return;
    int b = p >> 12, n = p & (NPTS - 1);
    #pragma unroll
    for (int c = 0; c < 6; ++c)
        xyzT[(size_t)p * 6 + c] = x[((size_t)b * 6 + c) * NPTS + n];
}

// ---------------- row squared norms ----------------
__global__ __launch_bounds__(256) void k_row_norms(const float* __restrict__ f, int stride, int C, float* __restrict__ xx)
{
    int p = blockIdx.x * 256 + threadIdx.x;
    if (p >= NTOT) return;
    const float* r = f + (size_t)p * stride;
    float s = 0.f;
    for (int c = 0; c < C; ++c) { float v = r[c]; s += v * v; }
    xx[p] = s;
}

// ---------------- weight transpose (O,CK) -> (CK,O) ----------------
__global__ __launch_bounds__(256) void k_transpose_w(const float* __restrict__ w, float* __restrict__ wt, int O, int CK)
{
    int e = blockIdx.x * 256 + threadIdx.x;
    if (e >= O * CK) return;
    int c = e / O, o = e - c * O;
    wt[e] = w[(size_t)o * CK + c];
}

// ---------------- pd GEMM: pd[c][q] = 2*dot(feat_c, feat_q) - xx[c], one batch ----------------
#define PD_FMA_BLOCK \
    { \
        float4 av = *(const float4*)&As[kk][lr * 4]; \
        float4 bv = *(const float4*)&Bs[kk][lk * 4]; \
        float a0 = av.x, a1 = av.y, a2 = av.z, a3 = av.w; \
        float b0 = bv.x, b1 = bv.y, b2 = bv.z, b3 = bv.w; \
        acc[0][0] += a0*b0; acc[0][1] += a0*b1; acc[0][2] += a0*b2; acc[0][3] += a0*b3; \
        acc[1][0] += a1*b0; acc[1][1] += a1*b1; acc[1][2] += a1*b2; acc[1][3] += a1*b3; \
        acc[2][0] += a2*b0; acc[2][1] += a2*b1; acc[2][2] += a2*b2; acc[2][3] += a2*b3; \
        acc[3][0] += a3*b0; acc[3][1] += a3*b1; acc[3][2] += a3*b2; acc[3][3] += a3*b3; \
    }

template<int CK>  // 64 or 4 (C=3 zero-padded)
__global__ __launch_bounds__(256) void k_pd_gemm(
    const float* __restrict__ feat, int fstride,   // batch base (4096 rows)
    const float* __restrict__ xxb,                 // batch norms (4096)
    float* __restrict__ pd)                        // [4096][4096]
{
    __shared__ __align__(16) float As[16][68];
    __shared__ __align__(16) float Bs[16][68];
    int tid = threadIdx.x;
    int tM = blockIdx.x * 64;   // candidate rows
    int tN = blockIdx.y * 64;   // query cols
    int lk = tid & 15, lr = tid >> 4;
    float acc[4][4];
    #pragma unroll
    for (int i = 0; i < 4; ++i)
        #pragma unroll
        for (int j = 0; j < 4; ++j) acc[i][j] = 0.f;

    if constexpr (CK == 64) {
        for (int k0 = 0; k0 < 64; k0 += 16) {
            #pragma unroll
            for (int i = 0; i < 4; ++i) {
                int r = lr + 16 * i;
                As[lk][r] = feat[(size_t)(tM + r) * fstride + k0 + lk];
                Bs[lk][r] = feat[(size_t)(tN + r) * fstride + k0 + lk];
            }
            __syncthreads();
            #pragma unroll
            for (int kk = 0; kk < 16; ++kk) PD_FMA_BLOCK
            __syncthreads();
        }
    } else {
        int r = tid >> 2, kk4 = tid & 3;
        As[kk4][r] = (kk4 < 3) ? feat[(size_t)(tM + r) * fstride + kk4] : 0.f;
        Bs[kk4][r] = (kk4 < 3) ? feat[(size_t)(tN + r) * fstride + kk4] : 0.f;
        __syncthreads();
        #pragma unroll
        for (int kk = 0; kk < 4; ++kk) PD_FMA_BLOCK
    }
    #pragma unroll
    for (int i = 0; i < 4; ++i) {
        int c = tM + lr * 4 + i;
        float xc = xxb[c];
        float4 v = make_float4(2.f*acc[i][0]-xc, 2.f*acc[i][1]-xc, 2.f*acc[i][2]-xc, 2.f*acc[i][3]-xc);
        *(float4*)&pd[(size_t)c * 4096 + tN + lk * 4] = v;
    }
}

// ---------------- kNN select: per (query, slice) top-20 VALUES via branchless min/max chain ----
// block = 32 queries x 1024 cands (blockIdx.y = quarter-chunk); thread = (q = tid&31, sl = tid>>5)
// -> per-thread 128-cand stream; 8-way in-block merge -> qlists[(gq)*4 + chunk][20] sorted desc.
__global__ __launch_bounds__(256) void k_knn_select(
    const float* __restrict__ pd, int b,
    float* __restrict__ qlists)
{
    __shared__ __align__(16) float sm[5120];     // stage 128*36=4608 | dump 256*20=5120
    float (*ds)[36] = (float(*)[36])sm;
    int tid = threadIdx.x;
    int q0 = blockIdx.x * 32;
    int schunk = blockIdx.y;
    int q = tid & 31, sl = tid >> 5;

    float lv[KNN];
    #pragma unroll
    for (int j = 0; j < KNN; ++j) lv[j] = -INFINITY;

    for (int t = 0; t < 8; ++t) {
        int c0 = schunk * 1024 + t * 128;
        __syncthreads();
        #pragma unroll
        for (int r = 0; r < 4; ++r) {
            int f = tid + 256 * r;
            int row = f >> 3, col4 = f & 7;
            *(float4*)&ds[row][col4 * 4] = *(const float4*)&pd[(size_t)(c0 + row) * 4096 + q0 + col4 * 4];
        }
        __syncthreads();
        #pragma unroll
        for (int i = 0; i < 16; ++i) {
            float cv = ds[sl * 16 + i][q];
            float prev = lv[0];
            lv[0] = fmaxf(lv[0], cv);
            #pragma unroll
            for (int j = 1; j < KNN; ++j) {
                float cur = lv[j];
                lv[j] = fminf(prev, fmaxf(cv, cur));
                prev = cur;
            }
        }
    }
    __syncthreads();
    #pragma unroll
    for (int j = 0; j < KNN; ++j) sm[tid * KNN + j] = lv[j];
    __syncthreads();
    if (tid < 32) {
        int hp[8] = {0,0,0,0,0,0,0,0};
        size_t obase = ((size_t)(b * 4096 + q0 + tid) * 4 + schunk) * KNN;
        #pragma unroll 1
        for (int r = 0; r < KNN; ++r) {
            float bv = -INFINITY; int bs = 0;
            #pragma unroll
            for (int s = 0; s < 8; ++s) {
                float v = sm[(s * 32 + tid) * KNN + hp[s]];
                if (v > bv) { bv = v; bs = s; }
            }
            qlists[obase + r] = bv;
            #pragma unroll
            for (int s = 0; s < 8; ++s) hp[s] += (bs == s);
        }
    }
}

// ---------------- kNN collect: v20 = global 20th value; append all cv >= v20 ----------------
__global__ __launch_bounds__(256) void k_knn_collect(
    const float* __restrict__ pd, int b,
    const float* __restrict__ qlists,
    int* __restrict__ gcnt,            // [NTOT]
    float* __restrict__ gval,          // [64][NTOT]
    int* __restrict__ gidx)            // [64][NTOT]
{
    __shared__ __align__(16) float sm[4608];
    __shared__ float v20s[32];
    float (*ds)[36] = (float(*)[36])sm;
    int tid = threadIdx.x;
    int q0 = blockIdx.x * 32;
    int schunk = blockIdx.y;

    if (tid < 32) {
        const float* ql = qlists + (size_t)(b * 4096 + q0 + tid) * 4 * KNN;
        int hp[4] = {0,0,0,0};
        float bv = -INFINITY;
        #pragma unroll 1
        for (int r = 0; r < KNN; ++r) {
            bv = -INFINITY; int bs = 0;
            #pragma unroll
            for (int s = 0; s < 4; ++s) {
                float v = ql[s * KNN + hp[s]];
                if (v > bv) { bv = v; bs = s; }
            }
            #pragma unroll
            for (int s = 0; s < 4; ++s) hp[s] += (bs == s);
        }
        v20s[tid] = bv;
    }
    __syncthreads();
    int q = tid & 31, sl = tid >> 5;
    float v20 = v20s[q];
    int gq = b * 4096 + q0 + q;

    for (int t = 0; t < 8; ++t) {
        int c0 = schunk * 1024 + t * 128;
        __syncthreads();
        #pragma unroll
        for (int r = 0; r < 4; ++r) {
            int f = tid + 256 * r;
            int row = f >> 3, col4 = f & 7;
            *(float4*)&ds[row][col4 * 4] = *(const float4*)&pd[(size_t)(c0 + row) * 4096 + q0 + col4 * 4];
        }
        __syncthreads();
        #pragma unroll
        for (int i = 0; i < 16; ++i) {
            float cv = ds[sl * 16 + i][q];
            if (cv >= v20) {
                int pos = atomicAdd(&gcnt[gq], 1);
                if (pos < 64) {
                    gval[(size_t)pos * NTOT + gq] = cv;
                    gidx[(size_t)pos * NTOT + gq] = c0 + sl * 16 + i;
                }
            }
        }
    }
}

// ---------------- kNN final: sort survivors by (val desc, idx asc), emit top-20 indices ------
__global__ __launch_bounds__(256) void k_knn_final(
    const int* __restrict__ gcnt,
    const float* __restrict__ gval,
    const int* __restrict__ gidx,
    int* __restrict__ idx_out)
{
    int gq = blockIdx.x * 256 + threadIdx.x;
    if (gq >= NTOT) return;
    int n = gcnt[gq]; n = n > 64 ? 64 : n;
    float lv[KNN]; int li[KNN];
    #pragma unroll
    for (int j = 0; j < KNN; ++j) { lv[j] = -INFINITY; li[j] = 0x7fffffff; }
    for (int e = 0; e < n; ++e) {
        float cv = gval[(size_t)e * NTOT + gq];
        int  ci = gidx[(size_t)e * NTOT + gq];
        #pragma unroll
        for (int j = 0; j < KNN; ++j) {
            bool sw = (cv > lv[j]) || (cv == lv[j] && ci < li[j]);
            float tf = lv[j]; int ti = li[j];
            lv[j] = sw ? cv : lv[j];  li[j] = sw ? ci : li[j];
            cv    = sw ? tf : cv;     ci    = sw ? ti : ci;
        }
    }
    #pragma unroll
    for (int j = 0; j < KNN; ++j) idx_out[(size_t)gq * KNN + j] = li[j];
}

// ---------------- edge conv: one block per point ----------------
template<int C, int O>
__global__ __launch_bounds__(256) void k_edge_conv(
    const float* __restrict__ in, int istride,
    const int* __restrict__ idx,
    const float* __restrict__ wt,   // (2C, O) transposed weights
    const float* __restrict__ gg, const float* __restrict__ bb,
    const float* __restrict__ mm, const float* __restrict__ vv,
    float* __restrict__ out, int ostride)
{
    constexpr int G = 256 / O;
    constexpr int KPT = KNN / G;
    __shared__ int   sidx[KNN];
    __shared__ float sctr[C];
    __shared__ float snbr[KNN][C];
    __shared__ float sred[2][256];
    int p = blockIdx.x;
    int b = p >> 12;
    int tid = threadIdx.x;
    const float* ctr_row = in + (size_t)p * istride;
    if (tid < KNN) sidx[tid] = idx[(size_t)p * KNN + tid];
    for (int e = tid; e < C; e += 256) sctr[e] = ctr_row[e];
    __syncthreads();
    for (int e = tid; e < KNN * C; e += 256) {
        int k = e / C, c = e - k * C;
        snbr[k][c] = in[((size_t)b * NPTS + sidx[k]) * istride + c];
    }
    __syncthreads();
    int o = tid % O, gid = tid / O;
    float q = 0.f;
    #pragma unroll 4
    for (int c = 0; c < C; ++c) q += (wt[(C + c) * O + o] - wt[c * O + o]) * sctr[c];
    float acc[KPT];
    #pragma unroll
    for (int k = 0; k < KPT; ++k) acc[k] = 0.f;
    #pragma unroll 4
    for (int c = 0; c < C; ++c) {
        float wv = wt[c * O + o];
        #pragma unroll
        for (int k = 0; k < KPT; ++k) acc[k] += wv * snbr[gid * KPT + k][c];
    }
    float mx = -INFINITY, mn = INFINITY;
    #pragma unroll
    for (int k = 0; k < KPT; ++k) { mx = fmaxf(mx, acc[k]); mn = fminf(mn, acc[k]); }
    sred[0][tid] = mx; sred[1][tid] = mn;
    __syncthreads();
    if (gid == 0) {
        #pragma unroll
        for (int g2 = 1; g2 < G; ++g2) { mx = fmaxf(mx, sred[0][g2 * O + o]); mn = fminf(mn, sred[1][g2 * O + o]); }
        float s = gg[o] * rsqrtf(vv[o] + 1e-5f);
        float d = bb[o] - mm[o] * s;
        float dotv = (s >= 0.f) ? mx : mn;
        float h = s * (dotv + q) + d;
        out[(size_t)p * ostride + o] = lrelu_f(h);
    }
}

// ---------------- color MLP (3 -> 64) ----------------
__global__ __launch_bounds__(256) void k_color(
    const float* __restrict__ xyzT,
    const float* __restrict__ w,
    const float* __restrict__ gg, const float* __restrict__ bb,
    const float* __restrict__ mm, const float* __restrict__ vv,
    float* __restrict__ out, int ostride)
{
    int t = blockIdx.x * 256 + threadIdx.x;
    int p = t >> 6, o = t & 63;
    if (p >= NTOT) return;
    const float* rgb = xyzT + (size_t)p * 6 + 3;
    float h = rgb[0] * w[o*3+0] + rgb[1] * w[o*3+1] + rgb[2] * w[o*3+2];
    float s = gg[o] * rsqrtf(vv[o] + 1e-5f);
    float d = bb[o] - mm[o] * s;
    out[(size_t)p * ostride + o] = lrelu_f(s * h + d);
}

// ---------------- fp32 tiled GEMM: out[m][o] = act( A[m][:] . W[o][:] ) ----------------
__global__ __launch_bounds__(256) void k_gemm(
    const float* __restrict__ A, int lda,
    const float* __restrict__ W,
    const float* __restrict__ gg, const float* __restrict__ bb,
    const float* __restrict__ mm, const float* __restrict__ vv,
    int bn_act,
    float* __restrict__ out, int ldo,
    int K, int O)
{
    __shared__ __align__(16) float As[16][68];
    __shared__ __align__(16) float Bs[16][68];
    int tid = threadIdx.x;
    int tM = blockIdx.x * 64;
    int tN = blockIdx.y * 64;
    int lk = tid & 15, lr = tid >> 4;
    float acc[4][4];
    #pragma unroll
    for (int i = 0; i < 4; ++i)
        #pragma unroll
        for (int j = 0; j < 4; ++j) acc[i][j] = 0.f;

    for (int k0 = 0; k0 < K; k0 += 16) {
        #pragma unroll
        for (int i = 0; i < 4; ++i) {
            int r = lr + 16 * i;
            As[lk][r] = A[(size_t)(tM + r) * lda + k0 + lk];
        }
        #pragma unroll
        for (int i = 0; i < 4; ++i) {
            int r = lr + 16 * i;
            int oo = tN + r;
            Bs[lk][r] = (oo < O) ? W[(size_t)oo * K + k0 + lk] : 0.f;
        }
        __syncthreads();
        #pragma unroll
        for (int kk = 0; kk < 16; ++kk) {
            float4 av = *(const float4*)&As[kk][lr * 4];
            float4 bv = *(const float4*)&Bs[kk][lk * 4];
            float a0 = av.x, a1 = av.y, a2 = av.z, a3 = av.w;
            float b0 = bv.x, b1 = bv.y, b2 = bv.z, b3 = bv.w;
            acc[0][0] += a0*b0; acc[0][1] += a0*b1; acc[0][2] += a0*b2; acc[0][3] += a0*b3;
            acc[1][0] += a1*b0; acc[1][1] += a1*b1; acc[1][2] += a1*b2; acc[1][3] += a1*b3;
            acc[2][0] += a2*b0; acc[2][1] += a2*b1; acc[2][2] += a2*b2; acc[2][3] += a2*b3;
            acc[3][0] += a3*b0; acc[3][1] += a3*b1; acc[3][2] += a3*b2; acc[3][3] += a3*b3;
        }
        __syncthreads();
    }
    int ty = lr, tx = lk;
    #pragma unroll
    for (int i = 0; i < 4; ++i) {
        int m = tM + ty * 4 + i;
        #pragma unroll
        for (int j = 0; j < 4; ++j) {
            int oo = tN + tx * 4 + j;
            if (oo < O) {
                float t = acc[i][j];
                if (bn_act) {
                    float s = gg[oo] * rsqrtf(vv[oo] + 1e-5f);
                    float d = bb[oo] - mm[oo] * s;
                    t = s * t + d;
                    t = t >= 0.f ? t : 0.2f * t;
                } else {
                    t += bb[oo];
                }
                out[(size_t)m * ldo + oo] = t;
            }
        }
    }
}

// ---------------- x5 (B*N,1024 cols of xcomb) -> d_out (B,1024,N) ----------------
__global__ __launch_bounds__(256) void k_transpose_x5(const float* __restrict__ xcomb, float* __restrict__ out_x5)
{
    __shared__ float t[64][65];
    int tM = blockIdx.x * 64;
    int tO = blockIdx.y * 64;
    int tid = threadIdx.x;
    #pragma unroll
    for (int i = 0; i < 16; ++i) {
        int e = tid + 256 * i;
        int rr = e >> 6, cc = e & 63;
        t[rr][cc] = xcomb[(size_t)(tM + rr) * 1408 + 384 + tO + cc];
    }
    __syncthreads();
    int b = tM >> 12, n0 = tM & (NPTS - 1);
    #pragma unroll
    for (int i = 0; i < 16; ++i) {
        int e = tid + 256 * i;
        int oo = e >> 6, nn = e & 63;
        out_x5[(size_t)b * 1024 * NPTS + (size_t)(tO + oo) * NPTS + n0 + nn] = t[nn][oo];
    }
}

extern "C" void kernel_launch(void* const* d_in, const int* in_sizes, int n_in,
                              void* d_out, int out_size, void* d_ws, size_t ws_size,
                              hipStream_t stream)
{
    const float* x = (const float*)d_in[0];
    const float* ew[4] = {(const float*)d_in[1],  (const float*)d_in[6],  (const float*)d_in[11], (const float*)d_in[16]};
    const float* eg[4] = {(const float*)d_in[2],  (const float*)d_in[7],  (const float*)d_in[12], (const float*)d_in[17]};
    const float* ebp[4]= {(const float*)d_in[3],  (const float*)d_in[8],  (const float*)d_in[13], (const float*)d_in[18]};
    const float* em[4] = {(const float*)d_in[4],  (const float*)d_in[9],  (const float*)d_in[14], (const float*)d_in[19]};
    const float* ev[4] = {(const float*)d_in[5],  (const float*)d_in[10], (const float*)d_in[15], (const float*)d_in[20]};
    const float* col_w = (const float*)d_in[21];
    const float* col_g = (const float*)d_in[22];
    const float* col_b = (const float*)d_in[23];
    const float* col_m = (const float*)d_in[24];
    const float* col_v = (const float*)d_in[25];
    const float* c5_w = (const float*)d_in[26]; const float* c5_g = (const float*)d_in[27];
    const float* c5_b = (const float*)d_in[28]; const float* c5_m = (const float*)d_in[29];
    const float* c5_v = (const float*)d_in[30];
    const float* c6_w = (const float*)d_in[31]; const float* c6_g = (const float*)d_in[32];
    const float* c6_b = (const float*)d_in[33]; const float* c6_m = (const float*)d_in[34];
    const float* c6_v = (const float*)d_in[35];
    const float* c7_w = (const float*)d_in[36]; const float* c7_g = (const float*)d_in[37];
    const float* c7_b = (const float*)d_in[38]; const float* c7_m = (const float*)d_in[39];
    const float* c7_v = (const float*)d_in[40];
    const float* c8_w = (const float*)d_in[41]; const float* c8_b = (const float*)d_in[42];

    // workspace layout (floats). Peak live set: x6 + xcomb = 120 MiB.
    float* ws    = (float*)d_ws;
    float* x6    = ws;                         // (B*N x 512), written at c6
    float* xcomb = ws + 8388608;               // (B*N x 1408): cols 0-383 x_cat, 384-1407 x5
    float* x7    = xcomb;                      // reuse xcomb after c6
    // early-phase aliases inside the (later) x6 region — all dead before c6 runs:
    float* xyzT  = ws;                         // (B*N x 6)        [0, 98304)
    float* xx    = ws + 98304;                 // (B*N)            [98304, 114688)
    int*   idxb  = (int*)(ws + 114688);        // (B*N x 20)       [114688, 442368)
    float* wtbuf = ws + 442368;                // up to 16384      [442368, 458752)
    float* qlists= ws + 458752;                // (B*N x 4 x 20)   [458752, 1769472)
    int*   gcnt  = (int*)(ws + 1769472);       // (B*N)            [1769472, 1785856)
    float* gval  = ws + 1785856;               // (64 x B*N)       [1785856, 2834432)
    int*   gidx  = (int*)(ws + 2834432);       // (64 x B*N)       [2834432, 3883008)

    float* out_logits = (float*)d_out;                               // (B,N,13)
    float* out_x5     = (float*)d_out + (size_t)NBATCH * NPTS * 13;  // (B,1024,N)
    // pd scratch: exactly fills the x5 output region (dead until k_transpose_x5)
    float* pd = out_x5;                        // [4096][4096] per batch

    dim3 blk(256);
    dim3 pd_grid(64, 64);
    dim3 sel_grid(128, 4);

    k_transpose_in<<<dim3(NTOT/256), blk, 0, stream>>>(x, xyzT);

    // ---- ec1: input xyz (C=3, stride 6) -> xcomb cols 0..63 ----
    k_row_norms<<<dim3(NTOT/256), blk, 0, stream>>>(xyzT, 6, 3, xx);
    hipMemsetAsync(gcnt, 0, NTOT * sizeof(int), stream);
    for (int b = 0; b < NBATCH; ++b) {
        k_pd_gemm<4><<<pd_grid, blk, 0, stream>>>(xyzT + (size_t)b * NPTS * 6, 6, xx + b * NPTS, pd);
        k_knn_select<<<sel_grid, blk, 0, stream>>>(pd, b, qlists);
        k_knn_collect<<<sel_grid, blk, 0, stream>>>(pd, b, qlists, gcnt, gval, gidx);
    }
    k_knn_final<<<dim3(NTOT/256), blk, 0, stream>>>(gcnt, gval, gidx, idxb);
    k_transpose_w<<<dim3((64*6+255)/256), blk, 0, stream>>>(ew[0], wtbuf, 64, 6);
    k_edge_conv<3,64><<<dim3(NTOT), blk, 0, stream>>>(xyzT, 6, idxb, wtbuf,
        eg[0], ebp[0], em[0], ev[0], xcomb + 0, 1408);

    // ---- ec2: x1 (cols 0..63) -> cols 64..127 ----
    k_row_norms<<<dim3(NTOT/256), blk, 0, stream>>>(xcomb + 0, 1408, 64, xx);
    hipMemsetAsync(gcnt, 0, NTOT * sizeof(int), stream);
    for (int b = 0; b < NBATCH; ++b) {
        k_pd_gemm<64><<<pd_grid, blk, 0, stream>>>(xcomb + (size_t)b * NPTS * 1408, 1408, xx + b * NPTS, pd);
        k_knn_select<<<sel_grid, blk, 0, stream>>>(pd, b, qlists);
        k_knn_collect<<<sel_grid, blk, 0, stream>>>(pd, b, qlists, gcnt, gval, gidx);
    }
    k_knn_final<<<dim3(NTOT/256), blk, 0, stream>>>(gcnt, gval, gidx, idxb);
    k_transpose_w<<<dim3((64*128+255)/256), blk, 0, stream>>>(ew[1], wtbuf, 64, 128);
    k_edge_conv<64,64><<<dim3(NTOT), blk, 0, stream>>>(xcomb + 0, 1408, idxb, wtbuf,
        eg[1], ebp[1], em[1], ev[1], xcomb + 64, 1408);

    // ---- ec3: x2 (cols 64..127) -> cols 128..191 ----
    k_row_norms<<<dim3(NTOT/256), blk, 0, stream>>>(xcomb + 64, 1408, 64, xx);
    hipMemsetAsync(gcnt, 0, NTOT * sizeof(int), stream);
    for (int b = 0; b < NBATCH; ++b) {
        k_pd_gemm<64><<<pd_grid, blk, 0, stream>>>(xcomb + 64 + (size_t)b * NPTS * 1408, 1408, xx + b * NPTS, pd);
        k_knn_select<<<sel_grid, blk, 0, stream>>>(pd, b, qlists);
        k_knn_collect<<<sel_grid, blk, 0, stream>>>(pd, b, qlists, gcnt, gval, gidx);
    }
    k_knn_final<<<dim3(NTOT/256), blk, 0, stream>>>(gcnt, gval, gidx, idxb);
    k_transpose_w<<<dim3((64*128+255)/256), blk, 0, stream>>>(ew[2], wtbuf, 64, 128);
    k_edge_conv<64,64><<<dim3(NTOT), blk, 0, stream>>>(xcomb + 64, 1408, idxb, wtbuf,
        eg[2], ebp[2], em[2], ev[2], xcomb + 128, 1408);

    // ---- ec4: x3 (cols 128..191) -> cols 192..319 (O=128) ----
    k_row_norms<<<dim3(NTOT/256), blk, 0, stream>>>(xcomb + 128, 1408, 64, xx);
    hipMemsetAsync(gcnt, 0, NTOT * sizeof(int), stream);
    for (int b = 0; b < NBATCH; ++b) {
        k_pd_gemm<64><<<pd_grid, blk, 0, stream>>>(xcomb + 128 + (size_t)b * NPTS * 1408, 1408, xx + b * NPTS, pd);
        k_knn_select<<<sel_grid, blk, 0, stream>>>(pd, b, qlists);
        k_knn_collect<<<sel_grid, blk, 0, stream>>>(pd, b, qlists, gcnt, gval, gidx);
    }
    k_knn_final<<<dim3(NTOT/256), blk, 0, stream>>>(gcnt, gval, gidx, idxb);
    k_transpose_w<<<dim3((128*128+255)/256), blk, 0, stream>>>(ew[3], wtbuf, 128, 128);
    k_edge_conv<64,128><<<dim3(NTOT), blk, 0, stream>>>(xcomb + 128, 1408, idxb, wtbuf,
        eg[3], ebp[3], em[3], ev[3], xcomb + 192, 1408);

    // ---- color: rgb -> cols 320..383 ----
    k_color<<<dim3(NTOT*64/256), blk, 0, stream>>>(xyzT, col_w, col_g, col_b, col_m, col_v,
        xcomb + 320, 1408);

    // ---- c5: (384 -> 1024), out into xcomb cols 384..1407 ----
    k_gemm<<<dim3(NTOT/64, 1024/64), blk, 0, stream>>>(xcomb, 1408, c5_w,
        c5_g, c5_b, c5_m, c5_v, 1, xcomb + 384, 1408, 384, 1024);
    k_transpose_x5<<<dim3(NTOT/64, 1024/64), blk, 0, stream>>>(xcomb, out_x5);

    // ---- c6: (1408 -> 512) ----
    k_gemm<<<dim3(NTOT/64, 512/64), blk, 0, stream>>>(xcomb, 1408, c6_w,
        c6_g, c6_b, c6_m, c6_v, 1, x6, 512, 1408, 512);

    // ---- c7: (512 -> 256) ----
    k_gemm<<<dim3(NTOT/64, 256/64), blk, 0, stream>>>(x6, 512, c7_w,
        c7_g, c7_b, c7_m, c7_v, 1, x7, 256, 512, 256);

    // ---- c8: (256 -> 13) + bias, straight into d_out (B,N,13) ----
    k_gemm<<<dim3(NTOT/64, 1), blk, 0, stream>>>(x7, 256, c8_w,
        nullptr, c8_b, nullptr, nullptr, 0, out_logits, 13, 256, 13);
}

// Round 9
// 2346.986 us; speedup vs baseline: 1.1996x; 1.1996x over previous
//
#include <hip/hip_runtime.h>
#include <math.h>

#define NPTS 4096
#define NBATCH 4
#define NTOT (NBATCH*NPTS)
#define KNN 20

typedef __attribute__((ext_vector_type(8))) short short8v;
typedef __attribute__((ext_vector_type(4))) float f32x4;

__device__ __forceinline__ float lrelu_f(float h) { return h >= 0.f ? h : 0.2f * h; }

// fp32 -> bf16 bits, round-to-nearest-even (finite inputs)
__device__ __forceinline__ short f2bf(float f) {
    unsigned u = __float_as_uint(f);
    u += 0x7fffu + ((u >> 16) & 1u);
    return (short)(u >> 16);
}

// ---------------- x:(B,6,N) -> xyzT:(B*N,6) ----------------
__global__ __launch_bounds__(256) void k_transpose_in(const float* __restrict__ x, float* __restrict__ xyzT)
{
    int p = blockIdx.x * 256 + threadIdx.x;
    if (p >= NTOT) return;
    int b = p >> 12, n = p & (NPTS - 1);
    #pragma unroll
    for (int c = 0; c < 6; ++c)
        xyzT[(size_t)p * 6 + c] = x[((size_t)b * 6 + c) * NPTS + n];
}

// ---------------- row squared norms ----------------
__global__ __launch_bounds__(256) void k_row_norms(const float* __restrict__ f, int stride, int C, float* __restrict__ xx)
{
    int p = blockIdx.x * 256 + threadIdx.x;
    if (p >= NTOT) return;
    const float* r = f + (size_t)p * stride;
    float s = 0.f;
    for (int c = 0; c < C; ++c) { float v = r[c]; s += v * v; }
    xx[p] = s;
}

// ---------------- weight transpose (O,CK) -> (CK,O) ----------------
__global__ __launch_bounds__(256) void k_transpose_w(const float* __restrict__ w, float* __restrict__ wt, int O, int CK)
{
    int e = blockIdx.x * 256 + threadIdx.x;
    if (e >= O * CK) return;
    int c = e / O, o = e - c * O;
    wt[e] = w[(size_t)o * CK + c];
}

// ---------------- pd GEMM: pd[c][q] = 2*dot(feat_c, feat_q) - xx[c], one batch ----------------
#define PD_FMA_BLOCK \
    { \
        float4 av = *(const float4*)&As[kk][lr * 4]; \
        float4 bv = *(const float4*)&Bs[kk][lk * 4]; \
        float a0 = av.x, a1 = av.y, a2 = av.z, a3 = av.w; \
        float b0 = bv.x, b1 = bv.y, b2 = bv.z, b3 = bv.w; \
        acc[0][0] += a0*b0; acc[0][1] += a0*b1; acc[0][2] += a0*b2; acc[0][3] += a0*b3; \
        acc[1][0] += a1*b0; acc[1][1] += a1*b1; acc[1][2] += a1*b2; acc[1][3] += a1*b3; \
        acc[2][0] += a2*b0; acc[2][1] += a2*b1; acc[2][2] += a2*b2; acc[2][3] += a2*b3; \
        acc[3][0] += a3*b0; acc[3][1] += a3*b1; acc[3][2] += a3*b2; acc[3][3] += a3*b3; \
    }

template<int CK>  // 64 or 4 (C=3 zero-padded)
__global__ __launch_bounds__(256) void k_pd_gemm(
    const float* __restrict__ feat, int fstride,   // batch base (4096 rows)
    const float* __restrict__ xxb,                 // batch norms (4096)
    float* __restrict__ pd)                        // [4096][4096]
{
    __shared__ __align__(16) float As[16][68];
    __shared__ __align__(16) float Bs[16][68];
    int tid = threadIdx.x;
    int tM = blockIdx.x * 64;   // candidate rows
    int tN = blockIdx.y * 64;   // query cols
    int lk = tid & 15, lr = tid >> 4;
    float acc[4][4];
    #pragma unroll
    for (int i = 0; i < 4; ++i)
        #pragma unroll
        for (int j = 0; j < 4; ++j) acc[i][j] = 0.f;

    if constexpr (CK == 64) {
        for (int k0 = 0; k0 < 64; k0 += 16) {
            #pragma unroll
            for (int i = 0; i < 4; ++i) {
                int r = lr + 16 * i;
                As[lk][r] = feat[(size_t)(tM + r) * fstride + k0 + lk];
                Bs[lk][r] = feat[(size_t)(tN + r) * fstride + k0 + lk];
            }
            __syncthreads();
            #pragma unroll
            for (int kk = 0; kk < 16; ++kk) PD_FMA_BLOCK
            __syncthreads();
        }
    } else {
        int r = tid >> 2, kk4 = tid & 3;
        As[kk4][r] = (kk4 < 3) ? feat[(size_t)(tM + r) * fstride + kk4] : 0.f;
        Bs[kk4][r] = (kk4 < 3) ? feat[(size_t)(tN + r) * fstride + kk4] : 0.f;
        __syncthreads();
        #pragma unroll
        for (int kk = 0; kk < 4; ++kk) PD_FMA_BLOCK
    }
    #pragma unroll
    for (int i = 0; i < 4; ++i) {
        int c = tM + lr * 4 + i;
        float xc = xxb[c];
        float4 v = make_float4(2.f*acc[i][0]-xc, 2.f*acc[i][1]-xc, 2.f*acc[i][2]-xc, 2.f*acc[i][3]-xc);
        *(float4*)&pd[(size_t)c * 4096 + tN + lk * 4] = v;
    }
}

// ---------------- kNN select: per (query, slice) top-20 VALUES via branchless min/max chain ----
__global__ __launch_bounds__(256) void k_knn_select(
    const float* __restrict__ pd, int b,
    float* __restrict__ qlists)
{
    __shared__ __align__(16) float sm[5120];     // stage 128*36=4608 | dump 256*20=5120
    float (*ds)[36] = (float(*)[36])sm;
    int tid = threadIdx.x;
    int q0 = blockIdx.x * 32;
    int schunk = blockIdx.y;
    int q = tid & 31, sl = tid >> 5;

    float lv[KNN];
    #pragma unroll
    for (int j = 0; j < KNN; ++j) lv[j] = -INFINITY;

    for (int t = 0; t < 8; ++t) {
        int c0 = schunk * 1024 + t * 128;
        __syncthreads();
        #pragma unroll
        for (int r = 0; r < 4; ++r) {
            int f = tid + 256 * r;
            int row = f >> 3, col4 = f & 7;
            *(float4*)&ds[row][col4 * 4] = *(const float4*)&pd[(size_t)(c0 + row) * 4096 + q0 + col4 * 4];
        }
        __syncthreads();
        #pragma unroll
        for (int i = 0; i < 16; ++i) {
            float cv = ds[sl * 16 + i][q];
            float prev = lv[0];
            lv[0] = fmaxf(lv[0], cv);
            #pragma unroll
            for (int j = 1; j < KNN; ++j) {
                float cur = lv[j];
                lv[j] = fminf(prev, fmaxf(cv, cur));
                prev = cur;
            }
        }
    }
    __syncthreads();
    #pragma unroll
    for (int j = 0; j < KNN; ++j) sm[tid * KNN + j] = lv[j];
    __syncthreads();
    if (tid < 32) {
        int hp[8] = {0,0,0,0,0,0,0,0};
        size_t obase = ((size_t)(b * 4096 + q0 + tid) * 4 + schunk) * KNN;
        #pragma unroll 1
        for (int r = 0; r < KNN; ++r) {
            float bv = -INFINITY; int bs = 0;
            #pragma unroll
            for (int s = 0; s < 8; ++s) {
                float v = sm[(s * 32 + tid) * KNN + hp[s]];
                if (v > bv) { bv = v; bs = s; }
            }
            qlists[obase + r] = bv;
            #pragma unroll
            for (int s = 0; s < 8; ++s) hp[s] += (bs == s);
        }
    }
}

// ---------------- kNN collect: v20 = global 20th value; append all cv >= v20 ----------------
__global__ __launch_bounds__(256) void k_knn_collect(
    const float* __restrict__ pd, int b,
    const float* __restrict__ qlists,
    int* __restrict__ gcnt,            // [NTOT]
    float* __restrict__ gval,          // [64][NTOT]
    int* __restrict__ gidx)            // [64][NTOT]
{
    __shared__ __align__(16) float sm[4608];
    __shared__ float v20s[32];
    float (*ds)[36] = (float(*)[36])sm;
    int tid = threadIdx.x;
    int q0 = blockIdx.x * 32;
    int schunk = blockIdx.y;

    if (tid < 32) {
        const float* ql = qlists + (size_t)(b * 4096 + q0 + tid) * 4 * KNN;
        int hp[4] = {0,0,0,0};
        float bv = -INFINITY;
        #pragma unroll 1
        for (int r = 0; r < KNN; ++r) {
            bv = -INFINITY; int bs = 0;
            #pragma unroll
            for (int s = 0; s < 4; ++s) {
                float v = ql[s * KNN + hp[s]];
                if (v > bv) { bv = v; bs = s; }
            }
            #pragma unroll
            for (int s = 0; s < 4; ++s) hp[s] += (bs == s);
        }
        v20s[tid] = bv;
    }
    __syncthreads();
    int q = tid & 31, sl = tid >> 5;
    float v20 = v20s[q];
    int gq = b * 4096 + q0 + q;

    for (int t = 0; t < 8; ++t) {
        int c0 = schunk * 1024 + t * 128;
        __syncthreads();
        #pragma unroll
        for (int r = 0; r < 4; ++r) {
            int f = tid + 256 * r;
            int row = f >> 3, col4 = f & 7;
            *(float4*)&ds[row][col4 * 4] = *(const float4*)&pd[(size_t)(c0 + row) * 4096 + q0 + col4 * 4];
        }
        __syncthreads();
        #pragma unroll
        for (int i = 0; i < 16; ++i) {
            float cv = ds[sl * 16 + i][q];
            if (cv >= v20) {
                int pos = atomicAdd(&gcnt[gq], 1);
                if (pos < 64) {
                    gval[(size_t)pos * NTOT + gq] = cv;
                    gidx[(size_t)pos * NTOT + gq] = c0 + sl * 16 + i;
                }
            }
        }
    }
}

// ---------------- kNN final: sort survivors by (val desc, idx asc), emit top-20 indices ------
__global__ __launch_bounds__(256) void k_knn_final(
    const int* __restrict__ gcnt,
    const float* __restrict__ gval,
    const int* __restrict__ gidx,
    int* __restrict__ idx_out)
{
    int gq = blockIdx.x * 256 + threadIdx.x;
    if (gq >= NTOT) return;
    int n = gcnt[gq]; n = n > 64 ? 64 : n;
    float lv[KNN]; int li[KNN];
    #pragma unroll
    for (int j = 0; j < KNN; ++j) { lv[j] = -INFINITY; li[j] = 0x7fffffff; }
    for (int e = 0; e < n; ++e) {
        float cv = gval[(size_t)e * NTOT + gq];
        int  ci = gidx[(size_t)e * NTOT + gq];
        #pragma unroll
        for (int j = 0; j < KNN; ++j) {
            bool sw = (cv > lv[j]) || (cv == lv[j] && ci < li[j]);
            float tf = lv[j]; int ti = li[j];
            lv[j] = sw ? cv : lv[j];  li[j] = sw ? ci : li[j];
            cv    = sw ? tf : cv;     ci    = sw ? ti : ci;
        }
    }
    #pragma unroll
    for (int j = 0; j < KNN; ++j) idx_out[(size_t)gq * KNN + j] = li[j];
}

// ---------------- edge conv: one block per point ----------------
template<int C, int O>
__global__ __launch_bounds__(256) void k_edge_conv(
    const float* __restrict__ in, int istride,
    const int* __restrict__ idx,
    const float* __restrict__ wt,   // (2C, O) transposed weights
    const float* __restrict__ gg, const float* __restrict__ bb,
    const float* __restrict__ mm, const float* __restrict__ vv,
    float* __restrict__ out, int ostride)
{
    constexpr int G = 256 / O;
    constexpr int KPT = KNN / G;
    __shared__ int   sidx[KNN];
    __shared__ float sctr[C];
    __shared__ float snbr[KNN][C];
    __shared__ float sred[2][256];
    int p = blockIdx.x;
    int b = p >> 12;
    int tid = threadIdx.x;
    const float* ctr_row = in + (size_t)p * istride;
    if (tid < KNN) sidx[tid] = idx[(size_t)p * KNN + tid];
    for (int e = tid; e < C; e += 256) sctr[e] = ctr_row[e];
    __syncthreads();
    for (int e = tid; e < KNN * C; e += 256) {
        int k = e / C, c = e - k * C;
        snbr[k][c] = in[((size_t)b * NPTS + sidx[k]) * istride + c];
    }
    __syncthreads();
    int o = tid % O, gid = tid / O;
    float q = 0.f;
    #pragma unroll 4
    for (int c = 0; c < C; ++c) q += (wt[(C + c) * O + o] - wt[c * O + o]) * sctr[c];
    float acc[KPT];
    #pragma unroll
    for (int k = 0; k < KPT; ++k) acc[k] = 0.f;
    #pragma unroll 4
    for (int c = 0; c < C; ++c) {
        float wv = wt[c * O + o];
        #pragma unroll
        for (int k = 0; k < KPT; ++k) acc[k] += wv * snbr[gid * KPT + k][c];
    }
    float mx = -INFINITY, mn = INFINITY;
    #pragma unroll
    for (int k = 0; k < KPT; ++k) { mx = fmaxf(mx, acc[k]); mn = fminf(mn, acc[k]); }
    sred[0][tid] = mx; sred[1][tid] = mn;
    __syncthreads();
    if (gid == 0) {
        #pragma unroll
        for (int g2 = 1; g2 < G; ++g2) { mx = fmaxf(mx, sred[0][g2 * O + o]); mn = fminf(mn, sred[1][g2 * O + o]); }
        float s = gg[o] * rsqrtf(vv[o] + 1e-5f);
        float d = bb[o] - mm[o] * s;
        float dotv = (s >= 0.f) ? mx : mn;
        float h = s * (dotv + q) + d;
        out[(size_t)p * ostride + o] = lrelu_f(h);
    }
}

// ---------------- color MLP (3 -> 64) ----------------
__global__ __launch_bounds__(256) void k_color(
    const float* __restrict__ xyzT,
    const float* __restrict__ w,
    const float* __restrict__ gg, const float* __restrict__ bb,
    const float* __restrict__ mm, const float* __restrict__ vv,
    float* __restrict__ out, int ostride)
{
    int t = blockIdx.x * 256 + threadIdx.x;
    int p = t >> 6, o = t & 63;
    if (p >= NTOT) return;
    const float* rgb = xyzT + (size_t)p * 6 + 3;
    float h = rgb[0] * w[o*3+0] + rgb[1] * w[o*3+1] + rgb[2] * w[o*3+2];
    float s = gg[o] * rsqrtf(vv[o] + 1e-5f);
    float d = bb[o] - mm[o] * s;
    out[(size_t)p * ostride + o] = lrelu_f(s * h + d);
}

// ---------------- bf16 MFMA GEMM: out[m][o] = act( A[m][:] . W[o][:] ) ----------------
// A fp32 (M x K row-major, lda), W fp32 (O x K row-major); fp32->bf16 in staging.
// 128x128 tile, 4 waves (each 64x64 = 4x4 frags of 16x16), BK=64.
// LDS 16-B-group XOR swizzle (group ^= row&7) kills the stride-128B bank conflict.
// Requires: M%128==0, O%128==0, K%64==0.
__global__ __launch_bounds__(256) void k_gemm_mfma(
    const float* __restrict__ A, int lda,
    const float* __restrict__ W,
    const float* __restrict__ gg, const float* __restrict__ bb,
    const float* __restrict__ mm, const float* __restrict__ vv,
    float* __restrict__ out, int ldo,
    int K, int O)
{
    __shared__ short As[128 * 64];
    __shared__ short Bs[128 * 64];
    int tid = threadIdx.x;
    int tN = blockIdx.x * 128;   // N fastest: consecutive blocks reuse A-tile in L2
    int tM = blockIdx.y * 128;
    int l = tid & 63, w = tid >> 6;
    int wm = (w & 1) * 64, wn = (w >> 1) * 64;
    int lrow = l & 15, lgrp = l >> 4;

    f32x4 acc[4][4];
    #pragma unroll
    for (int mi = 0; mi < 4; ++mi)
        #pragma unroll
        for (int nj = 0; nj < 4; ++nj) acc[mi][nj] = (f32x4){0.f, 0.f, 0.f, 0.f};

    for (int k0 = 0; k0 < K; k0 += 64) {
        #pragma unroll
        for (int i = 0; i < 4; ++i) {
            int f = tid + 256 * i;          // 0..1023
            int r = f >> 3, g = f & 7;
            const float* srcA = A + (size_t)(tM + r) * lda + k0 + g * 8;
            const float* srcW = W + (size_t)(tN + r) * K   + k0 + g * 8;
            float4 a0 = *(const float4*)srcA;
            float4 a1 = *(const float4*)(srcA + 4);
            float4 w0 = *(const float4*)srcW;
            float4 w1 = *(const float4*)(srcW + 4);
            int dst = r * 64 + ((g ^ (r & 7)) * 8);
            short8v sa = { f2bf(a0.x), f2bf(a0.y), f2bf(a0.z), f2bf(a0.w),
                           f2bf(a1.x), f2bf(a1.y), f2bf(a1.z), f2bf(a1.w) };
            short8v sw = { f2bf(w0.x), f2bf(w0.y), f2bf(w0.z), f2bf(w0.w),
                           f2bf(w1.x), f2bf(w1.y), f2bf(w1.z), f2bf(w1.w) };
            *(short8v*)&As[dst] = sa;
            *(short8v*)&Bs[dst] = sw;
        }
        __syncthreads();
        #pragma unroll
        for (int kk = 0; kk < 2; ++kk) {
            short8v af[4], bfr[4];
            #pragma unroll
            for (int mi = 0; mi < 4; ++mi) {
                int row = wm + mi * 16 + lrow;
                int g = kk * 4 + lgrp;
                af[mi] = *(const short8v*)&As[row * 64 + ((g ^ (row & 7)) * 8)];
            }
            #pragma unroll
            for (int nj = 0; nj < 4; ++nj) {
                int row = wn + nj * 16 + lrow;
                int g = kk * 4 + lgrp;
                bfr[nj] = *(const short8v*)&Bs[row * 64 + ((g ^ (row & 7)) * 8)];
            }
            #pragma unroll
            for (int mi = 0; mi < 4; ++mi)
                #pragma unroll
                for (int nj = 0; nj < 4; ++nj)
                    acc[mi][nj] = __builtin_amdgcn_mfma_f32_16x16x32_bf16(af[mi], bfr[nj], acc[mi][nj], 0, 0, 0);
        }
        __syncthreads();
    }

    // C/D layout: col = lane&15, row = (lane>>4)*4 + e   [m89-verified]
    #pragma unroll
    for (int nj = 0; nj < 4; ++nj) {
        int oo = tN + wn + nj * 16 + lrow;
        float s = gg[oo] * rsqrtf(vv[oo] + 1e-5f);
        float d = bb[oo] - mm[oo] * s;
        #pragma unroll
        for (int mi = 0; mi < 4; ++mi) {
            int m0 = tM + wm + mi * 16 + lgrp * 4;
            #pragma unroll
            for (int e = 0; e < 4; ++e) {
                float t = s * acc[mi][nj][e] + d;
                t = t >= 0.f ? t : 0.2f * t;
                out[(size_t)(m0 + e) * ldo + oo] = t;
            }
        }
    }
}

// ---------------- fp32 tiled GEMM (kept for c8: O=13) ----------------
__global__ __launch_bounds__(256) void k_gemm(
    const float* __restrict__ A, int lda,
    const float* __restrict__ W,
    const float* __restrict__ gg, const float* __restrict__ bb,
    const float* __restrict__ mm, const float* __restrict__ vv,
    int bn_act,
    float* __restrict__ out, int ldo,
    int K, int O)
{
    __shared__ __align__(16) float As[16][68];
    __shared__ __align__(16) float Bs[16][68];
    int tid = threadIdx.x;
    int tM = blockIdx.x * 64;
    int tN = blockIdx.y * 64;
    int lk = tid & 15, lr = tid >> 4;
    float acc[4][4];
    #pragma unroll
    for (int i = 0; i < 4; ++i)
        #pragma unroll
        for (int j = 0; j < 4; ++j) acc[i][j] = 0.f;

    for (int k0 = 0; k0 < K; k0 += 16) {
        #pragma unroll
        for (int i = 0; i < 4; ++i) {
            int r = lr + 16 * i;
            As[lk][r] = A[(size_t)(tM + r) * lda + k0 + lk];
        }
        #pragma unroll
        for (int i = 0; i < 4; ++i) {
            int r = lr + 16 * i;
            int oo = tN + r;
            Bs[lk][r] = (oo < O) ? W[(size_t)oo * K + k0 + lk] : 0.f;
        }
        __syncthreads();
        #pragma unroll
        for (int kk = 0; kk < 16; ++kk) {
            float4 av = *(const float4*)&As[kk][lr * 4];
            float4 bv = *(const float4*)&Bs[kk][lk * 4];
            float a0 = av.x, a1 = av.y, a2 = av.z, a3 = av.w;
            float b0 = bv.x, b1 = bv.y, b2 = bv.z, b3 = bv.w;
            acc[0][0] += a0*b0; acc[0][1] += a0*b1; acc[0][2] += a0*b2; acc[0][3] += a0*b3;
            acc[1][0] += a1*b0; acc[1][1] += a1*b1; acc[1][2] += a1*b2; acc[1][3] += a1*b3;
            acc[2][0] += a2*b0; acc[2][1] += a2*b1; acc[2][2] += a2*b2; acc[2][3] += a2*b3;
            acc[3][0] += a3*b0; acc[3][1] += a3*b1; acc[3][2] += a3*b2; acc[3][3] += a3*b3;
        }
        __syncthreads();
    }
    int ty = lr, tx = lk;
    #pragma unroll
    for (int i = 0; i < 4; ++i) {
        int m = tM + ty * 4 + i;
        #pragma unroll
        for (int j = 0; j < 4; ++j) {
            int oo = tN + tx * 4 + j;
            if (oo < O) {
                float t = acc[i][j];
                if (bn_act) {
                    float s = gg[oo] * rsqrtf(vv[oo] + 1e-5f);
                    float d = bb[oo] - mm[oo] * s;
                    t = s * t + d;
                    t = t >= 0.f ? t : 0.2f * t;
                } else {
                    t += bb[oo];
                }
                out[(size_t)m * ldo + oo] = t;
            }
        }
    }
}

// ---------------- x5 (B*N,1024 cols of xcomb) -> d_out (B,1024,N) ----------------
__global__ __launch_bounds__(256) void k_transpose_x5(const float* __restrict__ xcomb, float* __restrict__ out_x5)
{
    __shared__ float t[64][65];
    int tM = blockIdx.x * 64;
    int tO = blockIdx.y * 64;
    int tid = threadIdx.x;
    #pragma unroll
    for (int i = 0; i < 16; ++i) {
        int e = tid + 256 * i;
        int rr = e >> 6, cc = e & 63;
        t[rr][cc] = xcomb[(size_t)(tM + rr) * 1408 + 384 + tO + cc];
    }
    __syncthreads();
    int b = tM >> 12, n0 = tM & (NPTS - 1);
    #pragma unroll
    for (int i = 0; i < 16; ++i) {
        int e = tid + 256 * i;
        int oo = e >> 6, nn = e & 63;
        out_x5[(size_t)b * 1024 * NPTS + (size_t)(tO + oo) * NPTS + n0 + nn] = t[nn][oo];
    }
}

extern "C" void kernel_launch(void* const* d_in, const int* in_sizes, int n_in,
                              void* d_out, int out_size, void* d_ws, size_t ws_size,
                              hipStream_t stream)
{
    const float* x = (const float*)d_in[0];
    const float* ew[4] = {(const float*)d_in[1],  (const float*)d_in[6],  (const float*)d_in[11], (const float*)d_in[16]};
    const float* eg[4] = {(const float*)d_in[2],  (const float*)d_in[7],  (const float*)d_in[12], (const float*)d_in[17]};
    const float* ebp[4]= {(const float*)d_in[3],  (const float*)d_in[8],  (const float*)d_in[13], (const float*)d_in[18]};
    const float* em[4] = {(const float*)d_in[4],  (const float*)d_in[9],  (const float*)d_in[14], (const float*)d_in[19]};
    const float* ev[4] = {(const float*)d_in[5],  (const float*)d_in[10], (const float*)d_in[15], (const float*)d_in[20]};
    const float* col_w = (const float*)d_in[21];
    const float* col_g = (const float*)d_in[22];
    const float* col_b = (const float*)d_in[23];
    const float* col_m = (const float*)d_in[24];
    const float* col_v = (const float*)d_in[25];
    const float* c5_w = (const float*)d_in[26]; const float* c5_g = (const float*)d_in[27];
    const float* c5_b = (const float*)d_in[28]; const float* c5_m = (const float*)d_in[29];
    const float* c5_v = (const float*)d_in[30];
    const float* c6_w = (const float*)d_in[31]; const float* c6_g = (const float*)d_in[32];
    const float* c6_b = (const float*)d_in[33]; const float* c6_m = (const float*)d_in[34];
    const float* c6_v = (const float*)d_in[35];
    const float* c7_w = (const float*)d_in[36]; const float* c7_g = (const float*)d_in[37];
    const float* c7_b = (const float*)d_in[38]; const float* c7_m = (const float*)d_in[39];
    const float* c7_v = (const float*)d_in[40];
    const float* c8_w = (const float*)d_in[41]; const float* c8_b = (const float*)d_in[42];

    // workspace layout (floats). Peak live set: x6 + xcomb = 120 MiB.
    float* ws    = (float*)d_ws;
    float* x6    = ws;                         // (B*N x 512), written at c6
    float* xcomb = ws + 8388608;               // (B*N x 1408): cols 0-383 x_cat, 384-1407 x5
    float* x7    = xcomb;                      // reuse xcomb after c6
    // early-phase aliases inside the (later) x6 region — all dead before c6 runs:
    float* xyzT  = ws;                         // (B*N x 6)        [0, 98304)
    float* xx    = ws + 98304;                 // (B*N)            [98304, 114688)
    int*   idxb  = (int*)(ws + 114688);        // (B*N x 20)       [114688, 442368)
    float* wtbuf = ws + 442368;                // up to 32768      [442368, 475136) (overlaps dead qlists for ec4)
    float* qlists= ws + 458752;                // (B*N x 4 x 20)   [458752, 1769472)
    int*   gcnt  = (int*)(ws + 1769472);       // (B*N)            [1769472, 1785856)
    float* gval  = ws + 1785856;               // (64 x B*N)       [1785856, 2834432)
    int*   gidx  = (int*)(ws + 2834432);       // (64 x B*N)       [2834432, 3883008)

    float* out_logits = (float*)d_out;                               // (B,N,13)
    float* out_x5     = (float*)d_out + (size_t)NBATCH * NPTS * 13;  // (B,1024,N)
    // pd scratch: exactly fills the x5 output region (dead until k_transpose_x5)
    float* pd = out_x5;                        // [4096][4096] per batch

    dim3 blk(256);
    dim3 pd_grid(64, 64);
    dim3 sel_grid(128, 4);

    k_transpose_in<<<dim3(NTOT/256), blk, 0, stream>>>(x, xyzT);

    // ---- ec1: input xyz (C=3, stride 6) -> xcomb cols 0..63 ----
    k_row_norms<<<dim3(NTOT/256), blk, 0, stream>>>(xyzT, 6, 3, xx);
    hipMemsetAsync(gcnt, 0, NTOT * sizeof(int), stream);
    for (int b = 0; b < NBATCH; ++b) {
        k_pd_gemm<4><<<pd_grid, blk, 0, stream>>>(xyzT + (size_t)b * NPTS * 6, 6, xx + b * NPTS, pd);
        k_knn_select<<<sel_grid, blk, 0, stream>>>(pd, b, qlists);
        k_knn_collect<<<sel_grid, blk, 0, stream>>>(pd, b, qlists, gcnt, gval, gidx);
    }
    k_knn_final<<<dim3(NTOT/256), blk, 0, stream>>>(gcnt, gval, gidx, idxb);
    k_transpose_w<<<dim3((64*6+255)/256), blk, 0, stream>>>(ew[0], wtbuf, 64, 6);
    k_edge_conv<3,64><<<dim3(NTOT), blk, 0, stream>>>(xyzT, 6, idxb, wtbuf,
        eg[0], ebp[0], em[0], ev[0], xcomb + 0, 1408);

    // ---- ec2: x1 (cols 0..63) -> cols 64..127 ----
    k_row_norms<<<dim3(NTOT/256), blk, 0, stream>>>(xcomb + 0, 1408, 64, xx);
    hipMemsetAsync(gcnt, 0, NTOT * sizeof(int), stream);
    for (int b = 0; b < NBATCH; ++b) {
        k_pd_gemm<64><<<pd_grid, blk, 0, stream>>>(xcomb + (size_t)b * NPTS * 1408, 1408, xx + b * NPTS, pd);
        k_knn_select<<<sel_grid, blk, 0, stream>>>(pd, b, qlists);
        k_knn_collect<<<sel_grid, blk, 0, stream>>>(pd, b, qlists, gcnt, gval, gidx);
    }
    k_knn_final<<<dim3(NTOT/256), blk, 0, stream>>>(gcnt, gval, gidx, idxb);
    k_transpose_w<<<dim3((64*128+255)/256), blk, 0, stream>>>(ew[1], wtbuf, 64, 128);
    k_edge_conv<64,64><<<dim3(NTOT), blk, 0, stream>>>(xcomb + 0, 1408, idxb, wtbuf,
        eg[1], ebp[1], em[1], ev[1], xcomb + 64, 1408);

    // ---- ec3: x2 (cols 64..127) -> cols 128..191 ----
    k_row_norms<<<dim3(NTOT/256), blk, 0, stream>>>(xcomb + 64, 1408, 64, xx);
    hipMemsetAsync(gcnt, 0, NTOT * sizeof(int), stream);
    for (int b = 0; b < NBATCH; ++b) {
        k_pd_gemm<64><<<pd_grid, blk, 0, stream>>>(xcomb + 64 + (size_t)b * NPTS * 1408, 1408, xx + b * NPTS, pd);
        k_knn_select<<<sel_grid, blk, 0, stream>>>(pd, b, qlists);
        k_knn_collect<<<sel_grid, blk, 0, stream>>>(pd, b, qlists, gcnt, gval, gidx);
    }
    k_knn_final<<<dim3(NTOT/256), blk, 0, stream>>>(gcnt, gval, gidx, idxb);
    k_transpose_w<<<dim3((64*128+255)/256), blk, 0, stream>>>(ew[2], wtbuf, 64, 128);
    k_edge_conv<64,64><<<dim3(NTOT), blk, 0, stream>>>(xcomb + 64, 1408, idxb, wtbuf,
        eg[2], ebp[2], em[2], ev[2], xcomb + 128, 1408);

    // ---- ec4: x3 (cols 128..191) -> cols 192..319 (O=128) ----
    k_row_norms<<<dim3(NTOT/256), blk, 0, stream>>>(xcomb + 128, 1408, 64, xx);
    hipMemsetAsync(gcnt, 0, NTOT * sizeof(int), stream);
    for (int b = 0; b < NBATCH; ++b) {
        k_pd_gemm<64><<<pd_grid, blk, 0, stream>>>(xcomb + 128 + (size_t)b * NPTS * 1408, 1408, xx + b * NPTS, pd);
        k_knn_select<<<sel_grid, blk, 0, stream>>>(pd, b, qlists);
        k_knn_collect<<<sel_grid, blk, 0, stream>>>(pd, b, qlists, gcnt, gval, gidx);
    }
    k_knn_final<<<dim3(NTOT/256), blk, 0, stream>>>(gcnt, gval, gidx, idxb);
    k_transpose_w<<<dim3((128*128+255)/256), blk, 0, stream>>>(ew[3], wtbuf, 128, 128);
    k_edge_conv<64,128><<<dim3(NTOT), blk, 0, stream>>>(xcomb + 128, 1408, idxb, wtbuf,
        eg[3], ebp[3], em[3], ev[3], xcomb + 192, 1408);

    // ---- color: rgb -> cols 320..383 ----
    k_color<<<dim3(NTOT*64/256), blk, 0, stream>>>(xyzT, col_w, col_g, col_b, col_m, col_v,
        xcomb + 320, 1408);

    // ---- c5: (384 -> 1024) bf16 MFMA, out into xcomb cols 384..1407 ----
    k_gemm_mfma<<<dim3(1024/128, NTOT/128), blk, 0, stream>>>(xcomb, 1408, c5_w,
        c5_g, c5_b, c5_m, c5_v, xcomb + 384, 1408, 384, 1024);
    k_transpose_x5<<<dim3(NTOT/64, 1024/64), blk, 0, stream>>>(xcomb, out_x5);

    // ---- c6: (1408 -> 512) bf16 MFMA ----
    k_gemm_mfma<<<dim3(512/128, NTOT/128), blk, 0, stream>>>(xcomb, 1408, c6_w,
        c6_g, c6_b, c6_m, c6_v, x6, 512, 1408, 512);

    // ---- c7: (512 -> 256) bf16 MFMA ----
    k_gemm_mfma<<<dim3(256/128, NTOT/128), blk, 0, stream>>>(x6, 512, c7_w,
        c7_g, c7_b, c7_m, c7_v, x7, 256, 512, 256);

    // ---- c8: (256 -> 13) + bias, straight into d_out (B,N,13) ----
    k_gemm<<<dim3(NTOT/64, 1), blk, 0, stream>>>(x7, 256, c8_w,
        nullptr, c8_b, nullptr, nullptr, 0, out_logits, 13, 256, 13);
}

// Round 10
// 2059.940 us; speedup vs baseline: 1.3667x; 1.1393x over previous
//
#include <hip/hip_runtime.h>
#include <math.h>

#define NPTS 4096
#define NBATCH 4
#define NTOT (NBATCH*NPTS)
#define KNN 20

typedef __attribute__((ext_vector_type(8))) short short8v;
typedef __attribute__((ext_vector_type(4))) float f32x4;

__device__ __forceinline__ float lrelu_f(float h) { return h >= 0.f ? h : 0.2f * h; }

// fp32 -> bf16 bits, round-to-nearest-even (finite inputs)
__device__ __forceinline__ short f2bf(float f) {
    unsigned u = __float_as_uint(f);
    u += 0x7fffu + ((u >> 16) & 1u);
    return (short)(u >> 16);
}

// ---------------- x:(B,6,N) -> xyzT:(B*N,6) ----------------
__global__ __launch_bounds__(256) void k_transpose_in(const float* __restrict__ x, float* __restrict__ xyzT)
{
    int p = blockIdx.x * 256 + threadIdx.x;
    if (p >= NTOT) return;
    int b = p >> 12, n = p & (NPTS - 1);
    #pragma unroll
    for (int c = 0; c < 6; ++c)
        xyzT[(size_t)p * 6 + c] = x[((size_t)b * 6 + c) * NPTS + n];
}

// ---------------- row squared norms ----------------
__global__ __launch_bounds__(256) void k_row_norms(const float* __restrict__ f, int stride, int C, float* __restrict__ xx)
{
    int p = blockIdx.x * 256 + threadIdx.x;
    if (p >= NTOT) return;
    const float* r = f + (size_t)p * stride;
    float s = 0.f;
    for (int c = 0; c < C; ++c) { float v = r[c]; s += v * v; }
    xx[p] = s;
}

// ---------------- build combined edge weights: wc = [W1 ; W2-W1], (2O x C) ----------------
__global__ __launch_bounds__(256) void k_make_wc(
    const float* __restrict__ w,   // (O, 2C) row-major
    float* __restrict__ wc,        // (2O, C) row-major
    int O, int C)
{
    int e = blockIdx.x * 256 + threadIdx.x;
    if (e >= 2 * O * C) return;
    int j = e / C, c = e - j * C;
    if (j < O) {
        wc[e] = w[(size_t)j * 2 * C + c];
    } else {
        int o = j - O;
        wc[e] = w[(size_t)o * 2 * C + C + c] - w[(size_t)o * 2 * C + c];
    }
}

// ---------------- ec1 GQ: (NTOT,6) xyz x (128,3) wc -> (NTOT,128) ----------------
__global__ __launch_bounds__(256) void k_gw_small(
    const float* __restrict__ xyzT,
    const float* __restrict__ wc,
    float* __restrict__ GQ)
{
    int t = blockIdx.x * 256 + threadIdx.x;
    int p = t >> 7, j = t & 127;
    if (p >= NTOT) return;
    const float* f = xyzT + (size_t)p * 6;
    GQ[(size_t)p * 128 + j] = f[0]*wc[j*3+0] + f[1]*wc[j*3+1] + f[2]*wc[j*3+2];
}

// ---------------- edge max: out[p][o] = lrelu(s*(sel_k GQ[nbr_k][o] + GQ[p][O+o]) + d) ----
template<int O>
__global__ __launch_bounds__(256) void k_edge_max(
    const float* __restrict__ GQ,      // (NTOT, 2O)
    const int* __restrict__ idx,       // (NTOT, 20) batch-local
    const float* __restrict__ gg, const float* __restrict__ bb,
    const float* __restrict__ mm, const float* __restrict__ vv,
    float* __restrict__ out, int ostride)
{
    int t = blockIdx.x * 256 + threadIdx.x;
    int p = t / O;
    int o = t - p * O;
    if (p >= NTOT) return;
    int b = p >> 12;
    const int* ip = idx + (size_t)p * KNN;
    float mx = -INFINITY, mn = INFINITY;
    #pragma unroll 5
    for (int k = 0; k < KNN; ++k) {
        int r = b * NPTS + ip[k];
        float v = GQ[(size_t)r * (2 * O) + o];
        mx = fmaxf(mx, v); mn = fminf(mn, v);
    }
    float s = gg[o] * rsqrtf(vv[o] + 1e-5f);
    float d = bb[o] - mm[o] * s;
    float q = GQ[(size_t)p * (2 * O) + O + o];
    float h = s * (((s >= 0.f) ? mx : mn) + q) + d;
    out[(size_t)p * ostride + o] = lrelu_f(h);
}

// ---------------- pd GEMM: pd[c][q] = 2*dot(feat_c, feat_q) - xx[c], one batch ----------------
#define PD_FMA_BLOCK \
    { \
        float4 av = *(const float4*)&As[kk][lr * 4]; \
        float4 bv = *(const float4*)&Bs[kk][lk * 4]; \
        float a0 = av.x, a1 = av.y, a2 = av.z, a3 = av.w; \
        float b0 = bv.x, b1 = bv.y, b2 = bv.z, b3 = bv.w; \
        acc[0][0] += a0*b0; acc[0][1] += a0*b1; acc[0][2] += a0*b2; acc[0][3] += a0*b3; \
        acc[1][0] += a1*b0; acc[1][1] += a1*b1; acc[1][2] += a1*b2; acc[1][3] += a1*b3; \
        acc[2][0] += a2*b0; acc[2][1] += a2*b1; acc[2][2] += a2*b2; acc[2][3] += a2*b3; \
        acc[3][0] += a3*b0; acc[3][1] += a3*b1; acc[3][2] += a3*b2; acc[3][3] += a3*b3; \
    }

template<int CK>  // 64 or 4 (C=3 zero-padded)
__global__ __launch_bounds__(256) void k_pd_gemm(
    const float* __restrict__ feat, int fstride,   // batch base (4096 rows)
    const float* __restrict__ xxb,                 // batch norms (4096)
    float* __restrict__ pd)                        // [4096][4096]
{
    __shared__ __align__(16) float As[16][68];
    __shared__ __align__(16) float Bs[16][68];
    int tid = threadIdx.x;
    int tM = blockIdx.x * 64;   // candidate rows
    int tN = blockIdx.y * 64;   // query cols
    int lk = tid & 15, lr = tid >> 4;
    float acc[4][4];
    #pragma unroll
    for (int i = 0; i < 4; ++i)
        #pragma unroll
        for (int j = 0; j < 4; ++j) acc[i][j] = 0.f;

    if constexpr (CK == 64) {
        for (int k0 = 0; k0 < 64; k0 += 16) {
            #pragma unroll
            for (int i = 0; i < 4; ++i) {
                int r = lr + 16 * i;
                As[lk][r] = feat[(size_t)(tM + r) * fstride + k0 + lk];
                Bs[lk][r] = feat[(size_t)(tN + r) * fstride + k0 + lk];
            }
            __syncthreads();
            #pragma unroll
            for (int kk = 0; kk < 16; ++kk) PD_FMA_BLOCK
            __syncthreads();
        }
    } else {
        int r = tid >> 2, kk4 = tid & 3;
        As[kk4][r] = (kk4 < 3) ? feat[(size_t)(tM + r) * fstride + kk4] : 0.f;
        Bs[kk4][r] = (kk4 < 3) ? feat[(size_t)(tN + r) * fstride + kk4] : 0.f;
        __syncthreads();
        #pragma unroll
        for (int kk = 0; kk < 4; ++kk) PD_FMA_BLOCK
    }
    #pragma unroll
    for (int i = 0; i < 4; ++i) {
        int c = tM + lr * 4 + i;
        float xc = xxb[c];
        float4 v = make_float4(2.f*acc[i][0]-xc, 2.f*acc[i][1]-xc, 2.f*acc[i][2]-xc, 2.f*acc[i][3]-xc);
        *(float4*)&pd[(size_t)c * 4096 + tN + lk * 4] = v;
    }
}

// ---------------- kNN select: per (query, slice) top-20 VALUES via branchless min/max chain ----
__global__ __launch_bounds__(256) void k_knn_select(
    const float* __restrict__ pd, int b,
    float* __restrict__ qlists)
{
    __shared__ __align__(16) float sm[5120];     // stage 128*36=4608 | dump 256*20=5120
    float (*ds)[36] = (float(*)[36])sm;
    int tid = threadIdx.x;
    int q0 = blockIdx.x * 32;
    int schunk = blockIdx.y;
    int q = tid & 31, sl = tid >> 5;

    float lv[KNN];
    #pragma unroll
    for (int j = 0; j < KNN; ++j) lv[j] = -INFINITY;

    for (int t = 0; t < 8; ++t) {
        int c0 = schunk * 1024 + t * 128;
        __syncthreads();
        #pragma unroll
        for (int r = 0; r < 4; ++r) {
            int f = tid + 256 * r;
            int row = f >> 3, col4 = f & 7;
            *(float4*)&ds[row][col4 * 4] = *(const float4*)&pd[(size_t)(c0 + row) * 4096 + q0 + col4 * 4];
        }
        __syncthreads();
        #pragma unroll
        for (int i = 0; i < 16; ++i) {
            float cv = ds[sl * 16 + i][q];
            float prev = lv[0];
            lv[0] = fmaxf(lv[0], cv);
            #pragma unroll
            for (int j = 1; j < KNN; ++j) {
                float cur = lv[j];
                lv[j] = fminf(prev, fmaxf(cv, cur));
                prev = cur;
            }
        }
    }
    __syncthreads();
    #pragma unroll
    for (int j = 0; j < KNN; ++j) sm[tid * KNN + j] = lv[j];
    __syncthreads();
    if (tid < 32) {
        int hp[8] = {0,0,0,0,0,0,0,0};
        size_t obase = ((size_t)(b * 4096 + q0 + tid) * 4 + schunk) * KNN;
        #pragma unroll 1
        for (int r = 0; r < KNN; ++r) {
            float bv = -INFINITY; int bs = 0;
            #pragma unroll
            for (int s = 0; s < 8; ++s) {
                float v = sm[(s * 32 + tid) * KNN + hp[s]];
                if (v > bv) { bv = v; bs = s; }
            }
            qlists[obase + r] = bv;
            #pragma unroll
            for (int s = 0; s < 8; ++s) hp[s] += (bs == s);
        }
    }
}

// ---------------- kNN collect: v20 = global 20th value; append all cv >= v20 ----------------
__global__ __launch_bounds__(256) void k_knn_collect(
    const float* __restrict__ pd, int b,
    const float* __restrict__ qlists,
    int* __restrict__ gcnt,            // [NTOT]
    float* __restrict__ gval,          // [64][NTOT]
    int* __restrict__ gidx)            // [64][NTOT]
{
    __shared__ __align__(16) float sm[4608];
    __shared__ float v20s[32];
    float (*ds)[36] = (float(*)[36])sm;
    int tid = threadIdx.x;
    int q0 = blockIdx.x * 32;
    int schunk = blockIdx.y;

    if (tid < 32) {
        const float* ql = qlists + (size_t)(b * 4096 + q0 + tid) * 4 * KNN;
        int hp[4] = {0,0,0,0};
        float bv = -INFINITY;
        #pragma unroll 1
        for (int r = 0; r < KNN; ++r) {
            bv = -INFINITY; int bs = 0;
            #pragma unroll
            for (int s = 0; s < 4; ++s) {
                float v = ql[s * KNN + hp[s]];
                if (v > bv) { bv = v; bs = s; }
            }
            #pragma unroll
            for (int s = 0; s < 4; ++s) hp[s] += (bs == s);
        }
        v20s[tid] = bv;
    }
    __syncthreads();
    int q = tid & 31, sl = tid >> 5;
    float v20 = v20s[q];
    int gq = b * 4096 + q0 + q;

    for (int t = 0; t < 8; ++t) {
        int c0 = schunk * 1024 + t * 128;
        __syncthreads();
        #pragma unroll
        for (int r = 0; r < 4; ++r) {
            int f = tid + 256 * r;
            int row = f >> 3, col4 = f & 7;
            *(float4*)&ds[row][col4 * 4] = *(const float4*)&pd[(size_t)(c0 + row) * 4096 + q0 + col4 * 4];
        }
        __syncthreads();
        #pragma unroll
        for (int i = 0; i < 16; ++i) {
            float cv = ds[sl * 16 + i][q];
            if (cv >= v20) {
                int pos = atomicAdd(&gcnt[gq], 1);
                if (pos < 64) {
                    gval[(size_t)pos * NTOT + gq] = cv;
                    gidx[(size_t)pos * NTOT + gq] = c0 + sl * 16 + i;
                }
            }
        }
    }
}

// ---------------- kNN final: sort survivors by (val desc, idx asc), emit top-20 indices ------
__global__ __launch_bounds__(256) void k_knn_final(
    const int* __restrict__ gcnt,
    const float* __restrict__ gval,
    const int* __restrict__ gidx,
    int* __restrict__ idx_out)
{
    int gq = blockIdx.x * 256 + threadIdx.x;
    if (gq >= NTOT) return;
    int n = gcnt[gq]; n = n > 64 ? 64 : n;
    float lv[KNN]; int li[KNN];
    #pragma unroll
    for (int j = 0; j < KNN; ++j) { lv[j] = -INFINITY; li[j] = 0x7fffffff; }
    for (int e = 0; e < n; ++e) {
        float cv = gval[(size_t)e * NTOT + gq];
        int  ci = gidx[(size_t)e * NTOT + gq];
        #pragma unroll
        for (int j = 0; j < KNN; ++j) {
            bool sw = (cv > lv[j]) || (cv == lv[j] && ci < li[j]);
            float tf = lv[j]; int ti = li[j];
            lv[j] = sw ? cv : lv[j];  li[j] = sw ? ci : li[j];
            cv    = sw ? tf : cv;     ci    = sw ? ti : ci;
        }
    }
    #pragma unroll
    for (int j = 0; j < KNN; ++j) idx_out[(size_t)gq * KNN + j] = li[j];
}

// ---------------- color MLP (3 -> 64) ----------------
__global__ __launch_bounds__(256) void k_color(
    const float* __restrict__ xyzT,
    const float* __restrict__ w,
    const float* __restrict__ gg, const float* __restrict__ bb,
    const float* __restrict__ mm, const float* __restrict__ vv,
    float* __restrict__ out, int ostride)
{
    int t = blockIdx.x * 256 + threadIdx.x;
    int p = t >> 6, o = t & 63;
    if (p >= NTOT) return;
    const float* rgb = xyzT + (size_t)p * 6 + 3;
    float h = rgb[0] * w[o*3+0] + rgb[1] * w[o*3+1] + rgb[2] * w[o*3+2];
    float s = gg[o] * rsqrtf(vv[o] + 1e-5f);
    float d = bb[o] - mm[o] * s;
    out[(size_t)p * ostride + o] = lrelu_f(s * h + d);
}

// ---------------- bf16 MFMA GEMM: out[m][o] = act( A[m][:] . W[o][:] ) ----------------
// 128x128 tile, 4 waves, BK=64, XOR-swizzled LDS. Requires M%128==0, O%128==0, K%64==0.
__global__ __launch_bounds__(256) void k_gemm_mfma(
    const float* __restrict__ A, int lda,
    const float* __restrict__ W,
    const float* __restrict__ gg, const float* __restrict__ bb,
    const float* __restrict__ mm, const float* __restrict__ vv,
    float* __restrict__ out, int ldo,
    int K, int O)
{
    __shared__ short As[128 * 64];
    __shared__ short Bs[128 * 64];
    int tid = threadIdx.x;
    int tN = blockIdx.x * 128;   // N fastest: consecutive blocks reuse A-tile in L2
    int tM = blockIdx.y * 128;
    int l = tid & 63, w = tid >> 6;
    int wm = (w & 1) * 64, wn = (w >> 1) * 64;
    int lrow = l & 15, lgrp = l >> 4;

    f32x4 acc[4][4];
    #pragma unroll
    for (int mi = 0; mi < 4; ++mi)
        #pragma unroll
        for (int nj = 0; nj < 4; ++nj) acc[mi][nj] = (f32x4){0.f, 0.f, 0.f, 0.f};

    for (int k0 = 0; k0 < K; k0 += 64) {
        #pragma unroll
        for (int i = 0; i < 4; ++i) {
            int f = tid + 256 * i;          // 0..1023
            int r = f >> 3, g = f & 7;
            const float* srcA = A + (size_t)(tM + r) * lda + k0 + g * 8;
            const float* srcW = W + (size_t)(tN + r) * K   + k0 + g * 8;
            float4 a0 = *(const float4*)srcA;
            float4 a1 = *(const float4*)(srcA + 4);
            float4 w0 = *(const float4*)srcW;
            float4 w1 = *(const float4*)(srcW + 4);
            int dst = r * 64 + ((g ^ (r & 7)) * 8);
            short8v sa = { f2bf(a0.x), f2bf(a0.y), f2bf(a0.z), f2bf(a0.w),
                           f2bf(a1.x), f2bf(a1.y), f2bf(a1.z), f2bf(a1.w) };
            short8v sw = { f2bf(w0.x), f2bf(w0.y), f2bf(w0.z), f2bf(w0.w),
                           f2bf(w1.x), f2bf(w1.y), f2bf(w1.z), f2bf(w1.w) };
            *(short8v*)&As[dst] = sa;
            *(short8v*)&Bs[dst] = sw;
        }
        __syncthreads();
        #pragma unroll
        for (int kk = 0; kk < 2; ++kk) {
            short8v af[4], bfr[4];
            #pragma unroll
            for (int mi = 0; mi < 4; ++mi) {
                int row = wm + mi * 16 + lrow;
                int g = kk * 4 + lgrp;
                af[mi] = *(const short8v*)&As[row * 64 + ((g ^ (row & 7)) * 8)];
            }
            #pragma unroll
            for (int nj = 0; nj < 4; ++nj) {
                int row = wn + nj * 16 + lrow;
                int g = kk * 4 + lgrp;
                bfr[nj] = *(const short8v*)&Bs[row * 64 + ((g ^ (row & 7)) * 8)];
            }
            #pragma unroll
            for (int mi = 0; mi < 4; ++mi)
                #pragma unroll
                for (int nj = 0; nj < 4; ++nj)
                    acc[mi][nj] = __builtin_amdgcn_mfma_f32_16x16x32_bf16(af[mi], bfr[nj], acc[mi][nj], 0, 0, 0);
        }
        __syncthreads();
    }

    // C/D layout: col = lane&15, row = (lane>>4)*4 + e   [m89-verified]
    #pragma unroll
    for (int nj = 0; nj < 4; ++nj) {
        int oo = tN + wn + nj * 16 + lrow;
        float s = gg[oo] * rsqrtf(vv[oo] + 1e-5f);
        float d = bb[oo] - mm[oo] * s;
        #pragma unroll
        for (int mi = 0; mi < 4; ++mi) {
            int m0 = tM + wm + mi * 16 + lgrp * 4;
            #pragma unroll
            for (int e = 0; e < 4; ++e) {
                float t = s * acc[mi][nj][e] + d;
                t = t >= 0.f ? t : 0.2f * t;
                out[(size_t)(m0 + e) * ldo + oo] = t;
            }
        }
    }
}

// ---------------- fp32 tiled GEMM: bn_act: 1=BN+lrelu, 0=+bias, 2=raw ----------------
__global__ __launch_bounds__(256) void k_gemm(
    const float* __restrict__ A, int lda,
    const float* __restrict__ W,
    const float* __restrict__ gg, const float* __restrict__ bb,
    const float* __restrict__ mm, const float* __restrict__ vv,
    int bn_act,
    float* __restrict__ out, int ldo,
    int K, int O)
{
    __shared__ __align__(16) float As[16][68];
    __shared__ __align__(16) float Bs[16][68];
    int tid = threadIdx.x;
    int tM = blockIdx.x * 64;
    int tN = blockIdx.y * 64;
    int lk = tid & 15, lr = tid >> 4;
    float acc[4][4];
    #pragma unroll
    for (int i = 0; i < 4; ++i)
        #pragma unroll
        for (int j = 0; j < 4; ++j) acc[i][j] = 0.f;

    for (int k0 = 0; k0 < K; k0 += 16) {
        #pragma unroll
        for (int i = 0; i < 4; ++i) {
            int r = lr + 16 * i;
            As[lk][r] = A[(size_t)(tM + r) * lda + k0 + lk];
        }
        #pragma unroll
        for (int i = 0; i < 4; ++i) {
            int r = lr + 16 * i;
            int oo = tN + r;
            Bs[lk][r] = (oo < O) ? W[(size_t)oo * K + k0 + lk] : 0.f;
        }
        __syncthreads();
        #pragma unroll
        for (int kk = 0; kk < 16; ++kk) {
            float4 av = *(const float4*)&As[kk][lr * 4];
            float4 bv = *(const float4*)&Bs[kk][lk * 4];
            float a0 = av.x, a1 = av.y, a2 = av.z, a3 = av.w;
            float b0 = bv.x, b1 = bv.y, b2 = bv.z, b3 = bv.w;
            acc[0][0] += a0*b0; acc[0][1] += a0*b1; acc[0][2] += a0*b2; acc[0][3] += a0*b3;
            acc[1][0] += a1*b0; acc[1][1] += a1*b1; acc[1][2] += a1*b2; acc[1][3] += a1*b3;
            acc[2][0] += a2*b0; acc[2][1] += a2*b1; acc[2][2] += a2*b2; acc[2][3] += a2*b3;
            acc[3][0] += a3*b0; acc[3][1] += a3*b1; acc[3][2] += a3*b2; acc[3][3] += a3*b3;
        }
        __syncthreads();
    }
    int ty = lr, tx = lk;
    #pragma unroll
    for (int i = 0; i < 4; ++i) {
        int m = tM + ty * 4 + i;
        #pragma unroll
        for (int j = 0; j < 4; ++j) {
            int oo = tN + tx * 4 + j;
            if (oo < O) {
                float t = acc[i][j];
                if (bn_act == 1) {
                    float s = gg[oo] * rsqrtf(vv[oo] + 1e-5f);
                    float d = bb[oo] - mm[oo] * s;
                    t = s * t + d;
                    t = t >= 0.f ? t : 0.2f * t;
                } else if (bn_act == 0) {
                    t += bb[oo];
                }
                out[(size_t)m * ldo + oo] = t;
            }
        }
    }
}

// ---------------- x5 (B*N,1024 cols of xcomb) -> d_out (B,1024,N) ----------------
__global__ __launch_bounds__(256) void k_transpose_x5(const float* __restrict__ xcomb, float* __restrict__ out_x5)
{
    __shared__ float t[64][65];
    int tM = blockIdx.x * 64;
    int tO = blockIdx.y * 64;
    int tid = threadIdx.x;
    #pragma unroll
    for (int i = 0; i < 16; ++i) {
        int e = tid + 256 * i;
        int rr = e >> 6, cc = e & 63;
        t[rr][cc] = xcomb[(size_t)(tM + rr) * 1408 + 384 + tO + cc];
    }
    __syncthreads();
    int b = tM >> 12, n0 = tM & (NPTS - 1);
    #pragma unroll
    for (int i = 0; i < 16; ++i) {
        int e = tid + 256 * i;
        int oo = e >> 6, nn = e & 63;
        out_x5[(size_t)b * 1024 * NPTS + (size_t)(tO + oo) * NPTS + n0 + nn] = t[nn][oo];
    }
}

extern "C" void kernel_launch(void* const* d_in, const int* in_sizes, int n_in,
                              void* d_out, int out_size, void* d_ws, size_t ws_size,
                              hipStream_t stream)
{
    const float* x = (const float*)d_in[0];
    const float* ew[4] = {(const float*)d_in[1],  (const float*)d_in[6],  (const float*)d_in[11], (const float*)d_in[16]};
    const float* eg[4] = {(const float*)d_in[2],  (const float*)d_in[7],  (const float*)d_in[12], (const float*)d_in[17]};
    const float* ebp[4]= {(const float*)d_in[3],  (const float*)d_in[8],  (const float*)d_in[13], (const float*)d_in[18]};
    const float* em[4] = {(const float*)d_in[4],  (const float*)d_in[9],  (const float*)d_in[14], (const float*)d_in[19]};
    const float* ev[4] = {(const float*)d_in[5],  (const float*)d_in[10], (const float*)d_in[15], (const float*)d_in[20]};
    const float* col_w = (const float*)d_in[21];
    const float* col_g = (const float*)d_in[22];
    const float* col_b = (const float*)d_in[23];
    const float* col_m = (const float*)d_in[24];
    const float* col_v = (const float*)d_in[25];
    const float* c5_w = (const float*)d_in[26]; const float* c5_g = (const float*)d_in[27];
    const float* c5_b = (const float*)d_in[28]; const float* c5_m = (const float*)d_in[29];
    const float* c5_v = (const float*)d_in[30];
    const float* c6_w = (const float*)d_in[31]; const float* c6_g = (const float*)d_in[32];
    const float* c6_b = (const float*)d_in[33]; const float* c6_m = (const float*)d_in[34];
    const float* c6_v = (const float*)d_in[35];
    const float* c7_w = (const float*)d_in[36]; const float* c7_g = (const float*)d_in[37];
    const float* c7_b = (const float*)d_in[38]; const float* c7_m = (const float*)d_in[39];
    const float* c7_v = (const float*)d_in[40];
    const float* c8_w = (const float*)d_in[41]; const float* c8_b = (const float*)d_in[42];

    // workspace layout (floats). Peak live set: x6 + xcomb = 120 MiB.
    float* ws    = (float*)d_ws;
    float* x6    = ws;                         // (B*N x 512), written at c6
    float* xcomb = ws + 8388608;               // (B*N x 1408): cols 0-383 x_cat, 384-1407 x5
    float* x7    = xcomb;                      // reuse xcomb after c6
    // early-phase aliases inside the (later) x6 region — all dead before c6 runs:
    float* xyzT  = ws;                         // (B*N x 6)        [0, 98304)
    float* xx    = ws + 98304;                 // (B*N)            [98304, 114688)
    int*   idxb  = (int*)(ws + 114688);        // (B*N x 20)       [114688, 442368)
    float* wcbuf = ws + 442368;                // up to 16384      [442368, 458752)
    float* qlists= ws + 458752;                // (B*N x 4 x 20)   [458752, 1769472)
    int*   gcnt  = (int*)(ws + 1769472);       // (B*N)            [1769472, 1785856)
    float* gval  = ws + 1785856;               // (64 x B*N)       [1785856, 2834432)
    int*   gidx  = (int*)(ws + 2834432);       // (64 x B*N)       [2834432, 3883008)
    float* gq    = ws + 3883008;               // (B*N x up to 256)[3883008, 8077312)

    float* out_logits = (float*)d_out;                               // (B,N,13)
    float* out_x5     = (float*)d_out + (size_t)NBATCH * NPTS * 13;  // (B,1024,N)
    // pd scratch: exactly fills the x5 output region (dead until k_transpose_x5)
    float* pd = out_x5;                        // [4096][4096] per batch

    dim3 blk(256);
    dim3 pd_grid(64, 64);
    dim3 sel_grid(128, 4);

    k_transpose_in<<<dim3(NTOT/256), blk, 0, stream>>>(x, xyzT);

    // ---- ec1: input xyz (C=3, stride 6) -> xcomb cols 0..63 ----
    k_row_norms<<<dim3(NTOT/256), blk, 0, stream>>>(xyzT, 6, 3, xx);
    hipMemsetAsync(gcnt, 0, NTOT * sizeof(int), stream);
    for (int b = 0; b < NBATCH; ++b) {
        k_pd_gemm<4><<<pd_grid, blk, 0, stream>>>(xyzT + (size_t)b * NPTS * 6, 6, xx + b * NPTS, pd);
        k_knn_select<<<sel_grid, blk, 0, stream>>>(pd, b, qlists);
        k_knn_collect<<<sel_grid, blk, 0, stream>>>(pd, b, qlists, gcnt, gval, gidx);
    }
    k_knn_final<<<dim3(NTOT/256), blk, 0, stream>>>(gcnt, gval, gidx, idxb);
    k_make_wc<<<dim3((2*64*3+255)/256), blk, 0, stream>>>(ew[0], wcbuf, 64, 3);
    k_gw_small<<<dim3(NTOT*128/256), blk, 0, stream>>>(xyzT, wcbuf, gq);
    k_edge_max<64><<<dim3(NTOT*64/256), blk, 0, stream>>>(gq, idxb,
        eg[0], ebp[0], em[0], ev[0], xcomb + 0, 1408);

    // ---- ec2: x1 (cols 0..63) -> cols 64..127 ----
    k_row_norms<<<dim3(NTOT/256), blk, 0, stream>>>(xcomb + 0, 1408, 64, xx);
    hipMemsetAsync(gcnt, 0, NTOT * sizeof(int), stream);
    for (int b = 0; b < NBATCH; ++b) {
        k_pd_gemm<64><<<pd_grid, blk, 0, stream>>>(xcomb + (size_t)b * NPTS * 1408, 1408, xx + b * NPTS, pd);
        k_knn_select<<<sel_grid, blk, 0, stream>>>(pd, b, qlists);
        k_knn_collect<<<sel_grid, blk, 0, stream>>>(pd, b, qlists, gcnt, gval, gidx);
    }
    k_knn_final<<<dim3(NTOT/256), blk, 0, stream>>>(gcnt, gval, gidx, idxb);
    k_make_wc<<<dim3((2*64*64+255)/256), blk, 0, stream>>>(ew[1], wcbuf, 64, 64);
    k_gemm<<<dim3(NTOT/64, 128/64), blk, 0, stream>>>(xcomb + 0, 1408, wcbuf,
        nullptr, nullptr, nullptr, nullptr, 2, gq, 128, 64, 128);
    k_edge_max<64><<<dim3(NTOT*64/256), blk, 0, stream>>>(gq, idxb,
        eg[1], ebp[1], em[1], ev[1], xcomb + 64, 1408);

    // ---- ec3: x2 (cols 64..127) -> cols 128..191 ----
    k_row_norms<<<dim3(NTOT/256), blk, 0, stream>>>(xcomb + 64, 1408, 64, xx);
    hipMemsetAsync(gcnt, 0, NTOT * sizeof(int), stream);
    for (int b = 0; b < NBATCH; ++b) {
        k_pd_gemm<64><<<pd_grid, blk, 0, stream>>>(xcomb + 64 + (size_t)b * NPTS * 1408, 1408, xx + b * NPTS, pd);
        k_knn_select<<<sel_grid, blk, 0, stream>>>(pd, b, qlists);
        k_knn_collect<<<sel_grid, blk, 0, stream>>>(pd, b, qlists, gcnt, gval, gidx);
    }
    k_knn_final<<<dim3(NTOT/256), blk, 0, stream>>>(gcnt, gval, gidx, idxb);
    k_make_wc<<<dim3((2*64*64+255)/256), blk, 0, stream>>>(ew[2], wcbuf, 64, 64);
    k_gemm<<<dim3(NTOT/64, 128/64), blk, 0, stream>>>(xcomb + 64, 1408, wcbuf,
        nullptr, nullptr, nullptr, nullptr, 2, gq, 128, 64, 128);
    k_edge_max<64><<<dim3(NTOT*64/256), blk, 0, stream>>>(gq, idxb,
        eg[2], ebp[2], em[2], ev[2], xcomb + 128, 1408);

    // ---- ec4: x3 (cols 128..191) -> cols 192..319 (O=128) ----
    k_row_norms<<<dim3(NTOT/256), blk, 0, stream>>>(xcomb + 128, 1408, 64, xx);
    hipMemsetAsync(gcnt, 0, NTOT * sizeof(int), stream);
    for (int b = 0; b < NBATCH; ++b) {
        k_pd_gemm<64><<<pd_grid, blk, 0, stream>>>(xcomb + 128 + (size_t)b * NPTS * 1408, 1408, xx + b * NPTS, pd);
        k_knn_select<<<sel_grid, blk, 0, stream>>>(pd, b, qlists);
        k_knn_collect<<<sel_grid, blk, 0, stream>>>(pd, b, qlists, gcnt, gval, gidx);
    }
    k_knn_final<<<dim3(NTOT/256), blk, 0, stream>>>(gcnt, gval, gidx, idxb);
    k_make_wc<<<dim3((2*128*64+255)/256), blk, 0, stream>>>(ew[3], wcbuf, 128, 64);
    k_gemm<<<dim3(NTOT/64, 256/64), blk, 0, stream>>>(xcomb + 128, 1408, wcbuf,
        nullptr, nullptr, nullptr, nullptr, 2, gq, 256, 64, 256);
    k_edge_max<128><<<dim3(NTOT*128/256), blk, 0, stream>>>(gq, idxb,
        eg[3], ebp[3], em[3], ev[3], xcomb + 192, 1408);

    // ---- color: rgb -> cols 320..383 ----
    k_color<<<dim3(NTOT*64/256), blk, 0, stream>>>(xyzT, col_w, col_g, col_b, col_m, col_v,
        xcomb + 320, 1408);

    // ---- c5: (384 -> 1024) bf16 MFMA, out into xcomb cols 384..1407 ----
    k_gemm_mfma<<<dim3(1024/128, NTOT/128), blk, 0, stream>>>(xcomb, 1408, c5_w,
        c5_g, c5_b, c5_m, c5_v, xcomb + 384, 1408, 384, 1024);
    k_transpose_x5<<<dim3(NTOT/64, 1024/64), blk, 0, stream>>>(xcomb, out_x5);

    // ---- c6: (1408 -> 512) bf16 MFMA ----
    k_gemm_mfma<<<dim3(512/128, NTOT/128), blk, 0, stream>>>(xcomb, 1408, c6_w,
        c6_g, c6_b, c6_m, c6_v, x6, 512, 1408, 512);

    // ---- c7: (512 -> 256) bf16 MFMA ----
    k_gemm_mfma<<<dim3(256/128, NTOT/128), blk, 0, stream>>>(x6, 512, c7_w,
        c7_g, c7_b, c7_m, c7_v, x7, 256, 512, 256);

    // ---- c8: (256 -> 13) + bias, straight into d_out (B,N,13) ----
    k_gemm<<<dim3(NTOT/64, 1), blk, 0, stream>>>(x7, 256, c8_w,
        nullptr, c8_b, nullptr, nullptr, 0, out_logits, 13, 256, 13);
}

// Round 12
// 1941.322 us; speedup vs baseline: 1.4502x; 1.0611x over previous
//
#include <hip/hip_runtime.h>
#include <math.h>

#define NPTS 4096
#define NBATCH 4
#define NTOT (NBATCH*NPTS)
#define KNN 20

typedef __attribute__((ext_vector_type(8))) short short8v;
typedef __attribute__((ext_vector_type(4))) float f32x4;

__device__ __forceinline__ float lrelu_f(float h) { return h >= 0.f ? h : 0.2f * h; }

// fp32 -> bf16 bits, round-to-nearest-even (finite inputs)
__device__ __forceinline__ short f2bf(float f) {
    unsigned u = __float_as_uint(f);
    u += 0x7fffu + ((u >> 16) & 1u);
    return (short)(u >> 16);
}

// ---------------- x:(B,6,N) -> xyzT:(B*N,6) ----------------
__global__ __launch_bounds__(256) void k_transpose_in(const float* __restrict__ x, float* __restrict__ xyzT)
{
    int p = blockIdx.x * 256 + threadIdx.x;
    if (p >= NTOT) return;
    int b = p >> 12, n = p & (NPTS - 1);
    #pragma unroll
    for (int c = 0; c < 6; ++c)
        xyzT[(size_t)p * 6 + c] = x[((size_t)b * 6 + c) * NPTS + n];
}

// ---------------- row squared norms ----------------
__global__ __launch_bounds__(256) void k_row_norms(const float* __restrict__ f, int stride, int C, float* __restrict__ xx)
{
    int p = blockIdx.x * 256 + threadIdx.x;
    if (p >= NTOT) return;
    const float* r = f + (size_t)p * stride;
    float s = 0.f;
    for (int c = 0; c < C; ++c) { float v = r[c]; s += v * v; }
    xx[p] = s;
}

// ---------------- build combined edge weights: wc = [W1 ; W2-W1], (2O x C) ----------------
__global__ __launch_bounds__(256) void k_make_wc(
    const float* __restrict__ w,   // (O, 2C) row-major
    float* __restrict__ wc,        // (2O, C) row-major
    int O, int C)
{
    int e = blockIdx.x * 256 + threadIdx.x;
    if (e >= 2 * O * C) return;
    int j = e / C, c = e - j * C;
    if (j < O) {
        wc[e] = w[(size_t)j * 2 * C + c];
    } else {
        int o = j - O;
        wc[e] = w[(size_t)o * 2 * C + C + c] - w[(size_t)o * 2 * C + c];
    }
}

// ---------------- ec1 GQ: (NTOT,6) xyz x (128,3) wc -> (NTOT,128) ----------------
__global__ __launch_bounds__(256) void k_gw_small(
    const float* __restrict__ xyzT,
    const float* __restrict__ wc,
    float* __restrict__ GQ)
{
    int t = blockIdx.x * 256 + threadIdx.x;
    int p = t >> 7, j = t & 127;
    if (p >= NTOT) return;
    const float* f = xyzT + (size_t)p * 6;
    GQ[(size_t)p * 128 + j] = f[0]*wc[j*3+0] + f[1]*wc[j*3+1] + f[2]*wc[j*3+2];
}

// ---------------- edge max: out[p][o] = lrelu(s*(sel_k GQ[nbr_k][o] + GQ[p][O+o]) + d) ----
// writes bf16 to aout always; fp32 to out iff FOUT (kNN chain consumers)
template<int O, bool FOUT>
__global__ __launch_bounds__(256) void k_edge_max(
    const float* __restrict__ GQ,      // (NTOT, 2O)
    const int* __restrict__ idx,       // (NTOT, 20) batch-local
    const float* __restrict__ gg, const float* __restrict__ bb,
    const float* __restrict__ mm, const float* __restrict__ vv,
    float* __restrict__ out, int ostride,
    short* __restrict__ aout, int aostride)
{
    int t = blockIdx.x * 256 + threadIdx.x;
    int p = t / O;
    int o = t - p * O;
    if (p >= NTOT) return;
    int b = p >> 12;
    const int* ip = idx + (size_t)p * KNN;
    float mx = -INFINITY, mn = INFINITY;
    #pragma unroll 5
    for (int k = 0; k < KNN; ++k) {
        int r = b * NPTS + ip[k];
        float v = GQ[(size_t)r * (2 * O) + o];
        mx = fmaxf(mx, v); mn = fminf(mn, v);
    }
    float s = gg[o] * rsqrtf(vv[o] + 1e-5f);
    float d = bb[o] - mm[o] * s;
    float q = GQ[(size_t)p * (2 * O) + O + o];
    float h = s * (((s >= 0.f) ? mx : mn) + q) + d;
    float res = lrelu_f(h);
    if constexpr (FOUT) out[(size_t)p * ostride + o] = res;
    aout[(size_t)p * aostride + o] = f2bf(res);
}

// ---------------- pd GEMM: pd[c][q] = 2*dot(feat_c, feat_q) - xx[c], one batch ----------------
#define PD_FMA_BLOCK \
    { \
        float4 av = *(const float4*)&As[kk][lr * 4]; \
        float4 bv = *(const float4*)&Bs[kk][lk * 4]; \
        float a0 = av.x, a1 = av.y, a2 = av.z, a3 = av.w; \
        float b0 = bv.x, b1 = bv.y, b2 = bv.z, b3 = bv.w; \
        acc[0][0] += a0*b0; acc[0][1] += a0*b1; acc[0][2] += a0*b2; acc[0][3] += a0*b3; \
        acc[1][0] += a1*b0; acc[1][1] += a1*b1; acc[1][2] += a1*b2; acc[1][3] += a1*b3; \
        acc[2][0] += a2*b0; acc[2][1] += a2*b1; acc[2][2] += a2*b2; acc[2][3] += a2*b3; \
        acc[3][0] += a3*b0; acc[3][1] += a3*b1; acc[3][2] += a3*b2; acc[3][3] += a3*b3; \
    }

template<int CK>  // 64 or 4 (C=3 zero-padded)
__global__ __launch_bounds__(256) void k_pd_gemm(
    const float* __restrict__ feat, int fstride,   // batch base (4096 rows)
    const float* __restrict__ xxb,                 // batch norms (4096)
    float* __restrict__ pd)                        // [4096][4096]
{
    __shared__ __align__(16) float As[16][68];
    __shared__ __align__(16) float Bs[16][68];
    int tid = threadIdx.x;
    int tM = blockIdx.x * 64;   // candidate rows
    int tN = blockIdx.y * 64;   // query cols
    int lk = tid & 15, lr = tid >> 4;
    float acc[4][4];
    #pragma unroll
    for (int i = 0; i < 4; ++i)
        #pragma unroll
        for (int j = 0; j < 4; ++j) acc[i][j] = 0.f;

    if constexpr (CK == 64) {
        for (int k0 = 0; k0 < 64; k0 += 16) {
            #pragma unroll
            for (int i = 0; i < 4; ++i) {
                int r = lr + 16 * i;
                As[lk][r] = feat[(size_t)(tM + r) * fstride + k0 + lk];
                Bs[lk][r] = feat[(size_t)(tN + r) * fstride + k0 + lk];
            }
            __syncthreads();
            #pragma unroll
            for (int kk = 0; kk < 16; ++kk) PD_FMA_BLOCK
            __syncthreads();
        }
    } else {
        int r = tid >> 2, kk4 = tid & 3;
        As[kk4][r] = (kk4 < 3) ? feat[(size_t)(tM + r) * fstride + kk4] : 0.f;
        Bs[kk4][r] = (kk4 < 3) ? feat[(size_t)(tN + r) * fstride + kk4] : 0.f;
        __syncthreads();
        #pragma unroll
        for (int kk = 0; kk < 4; ++kk) PD_FMA_BLOCK
    }
    #pragma unroll
    for (int i = 0; i < 4; ++i) {
        int c = tM + lr * 4 + i;
        float xc = xxb[c];
        float4 v = make_float4(2.f*acc[i][0]-xc, 2.f*acc[i][1]-xc, 2.f*acc[i][2]-xc, 2.f*acc[i][3]-xc);
        *(float4*)&pd[(size_t)c * 4096 + tN + lk * 4] = v;
    }
}

// ---------------- kNN select: per (query, slice) top-20 VALUES via branchless min/max chain ----
__global__ __launch_bounds__(256) void k_knn_select(
    const float* __restrict__ pd, int b,
    float* __restrict__ qlists)
{
    __shared__ __align__(16) float sm[5120];     // stage 128*36=4608 | dump 256*20=5120
    float (*ds)[36] = (float(*)[36])sm;
    int tid = threadIdx.x;
    int q0 = blockIdx.x * 32;
    int schunk = blockIdx.y;
    int q = tid & 31, sl = tid >> 5;

    float lv[KNN];
    #pragma unroll
    for (int j = 0; j < KNN; ++j) lv[j] = -INFINITY;

    for (int t = 0; t < 8; ++t) {
        int c0 = schunk * 1024 + t * 128;
        __syncthreads();
        #pragma unroll
        for (int r = 0; r < 4; ++r) {
            int f = tid + 256 * r;
            int row = f >> 3, col4 = f & 7;
            *(float4*)&ds[row][col4 * 4] = *(const float4*)&pd[(size_t)(c0 + row) * 4096 + q0 + col4 * 4];
        }
        __syncthreads();
        #pragma unroll
        for (int i = 0; i < 16; ++i) {
            float cv = ds[sl * 16 + i][q];
            float prev = lv[0];
            lv[0] = fmaxf(lv[0], cv);
            #pragma unroll
            for (int j = 1; j < KNN; ++j) {
                float cur = lv[j];
                lv[j] = fminf(prev, fmaxf(cv, cur));
                prev = cur;
            }
        }
    }
    __syncthreads();
    #pragma unroll
    for (int j = 0; j < KNN; ++j) sm[tid * KNN + j] = lv[j];
    __syncthreads();
    if (tid < 32) {
        int hp[8] = {0,0,0,0,0,0,0,0};
        size_t obase = ((size_t)(b * 4096 + q0 + tid) * 4 + schunk) * KNN;
        #pragma unroll 1
        for (int r = 0; r < KNN; ++r) {
            float bv = -INFINITY; int bs = 0;
            #pragma unroll
            for (int s = 0; s < 8; ++s) {
                float v = sm[(s * 32 + tid) * KNN + hp[s]];
                if (v > bv) { bv = v; bs = s; }
            }
            qlists[obase + r] = bv;
            #pragma unroll
            for (int s = 0; s < 8; ++s) hp[s] += (bs == s);
        }
    }
}

// ---------------- kNN collect: v20 = global 20th value; append all cv >= v20 ----------------
__global__ __launch_bounds__(256) void k_knn_collect(
    const float* __restrict__ pd, int b,
    const float* __restrict__ qlists,
    int* __restrict__ gcnt,            // [NTOT]
    float* __restrict__ gval,          // [64][NTOT]
    int* __restrict__ gidx)            // [64][NTOT]
{
    __shared__ __align__(16) float sm[4608];
    __shared__ float v20s[32];
    float (*ds)[36] = (float(*)[36])sm;
    int tid = threadIdx.x;
    int q0 = blockIdx.x * 32;
    int schunk = blockIdx.y;

    if (tid < 32) {
        const float* ql = qlists + (size_t)(b * 4096 + q0 + tid) * 4 * KNN;
        int hp[4] = {0,0,0,0};
        float bv = -INFINITY;
        #pragma unroll 1
        for (int r = 0; r < KNN; ++r) {
            bv = -INFINITY; int bs = 0;
            #pragma unroll
            for (int s = 0; s < 4; ++s) {
                float v = ql[s * KNN + hp[s]];
                if (v > bv) { bv = v; bs = s; }
            }
            #pragma unroll
            for (int s = 0; s < 4; ++s) hp[s] += (bs == s);
        }
        v20s[tid] = bv;
    }
    __syncthreads();
    int q = tid & 31, sl = tid >> 5;
    float v20 = v20s[q];
    int gq = b * 4096 + q0 + q;

    for (int t = 0; t < 8; ++t) {
        int c0 = schunk * 1024 + t * 128;
        __syncthreads();
        #pragma unroll
        for (int r = 0; r < 4; ++r) {
            int f = tid + 256 * r;
            int row = f >> 3, col4 = f & 7;
            *(float4*)&ds[row][col4 * 4] = *(const float4*)&pd[(size_t)(c0 + row) * 4096 + q0 + col4 * 4];
        }
        __syncthreads();
        #pragma unroll
        for (int i = 0; i < 16; ++i) {
            float cv = ds[sl * 16 + i][q];
            if (cv >= v20) {
                int pos = atomicAdd(&gcnt[gq], 1);
                if (pos < 64) {
                    gval[(size_t)pos * NTOT + gq] = cv;
                    gidx[(size_t)pos * NTOT + gq] = c0 + sl * 16 + i;
                }
            }
        }
    }
}

// ---------------- kNN final: sort survivors by (val desc, idx asc), emit top-20 indices ------
__global__ __launch_bounds__(256) void k_knn_final(
    const int* __restrict__ gcnt,
    const float* __restrict__ gval,
    const int* __restrict__ gidx,
    int* __restrict__ idx_out)
{
    int gq = blockIdx.x * 256 + threadIdx.x;
    if (gq >= NTOT) return;
    int n = gcnt[gq]; n = n > 64 ? 64 : n;
    float lv[KNN]; int li[KNN];
    #pragma unroll
    for (int j = 0; j < KNN; ++j) { lv[j] = -INFINITY; li[j] = 0x7fffffff; }
    for (int e = 0; e < n; ++e) {
        float cv = gval[(size_t)e * NTOT + gq];
        int  ci = gidx[(size_t)e * NTOT + gq];
        #pragma unroll
        for (int j = 0; j < KNN; ++j) {
            bool sw = (cv > lv[j]) || (cv == lv[j] && ci < li[j]);
            float tf = lv[j]; int ti = li[j];
            lv[j] = sw ? cv : lv[j];  li[j] = sw ? ci : li[j];
            cv    = sw ? tf : cv;     ci    = sw ? ti : ci;
        }
    }
    #pragma unroll
    for (int j = 0; j < KNN; ++j) idx_out[(size_t)gq * KNN + j] = li[j];
}

// ---------------- color MLP (3 -> 64), bf16 out only ----------------
__global__ __launch_bounds__(256) void k_color(
    const float* __restrict__ xyzT,
    const float* __restrict__ w,
    const float* __restrict__ gg, const float* __restrict__ bb,
    const float* __restrict__ mm, const float* __restrict__ vv,
    short* __restrict__ aout, int aostride)
{
    int t = blockIdx.x * 256 + threadIdx.x;
    int p = t >> 6, o = t & 63;
    if (p >= NTOT) return;
    const float* rgb = xyzT + (size_t)p * 6 + 3;
    float h = rgb[0] * w[o*3+0] + rgb[1] * w[o*3+1] + rgb[2] * w[o*3+2];
    float s = gg[o] * rsqrtf(vv[o] + 1e-5f);
    float d = bb[o] - mm[o] * s;
    aout[(size_t)p * aostride + o] = f2bf(lrelu_f(s * h + d));
}

// ---------------- bf16-A MFMA GEMM: out[m][o] = lrelu(BN( A[m][:] . W[o][:] )) ----------------
// A bf16 (M x K row-major, lda in shorts), W fp32 (O x K). 128x128 tile, 4 waves, BK=64,
// XOR-swizzled LDS. Flat grid (O/128)*(M/128), x fastest, bijective XCD swizzle (nwg%8==0).
// MODE 0: fp32 out (ldo). MODE 1: bf16 out (ldo). MODE 2: bf16 out (ldo) + fp32 transposed
//         out2[(b*1024+o)*4096 + n]  (c5 -> d_out x5 region, M tiles never cross batches).
template<int MODE>
__global__ __launch_bounds__(256) void k_gemm_mfma(
    const short* __restrict__ A, int lda,
    const float* __restrict__ W,
    const float* __restrict__ gg, const float* __restrict__ bb,
    const float* __restrict__ mm, const float* __restrict__ vv,
    void* __restrict__ outp, int ldo,
    float* __restrict__ out2,
    int K, int O)
{
    __shared__ short As[128 * 64];
    __shared__ short Bs[128 * 64];
    int tid = threadIdx.x;
    int nxb = O >> 7;
    int nwg = nxb * (NTOT / 128);
    int bid = blockIdx.x;
    int swz = (bid & 7) * (nwg >> 3) + (bid >> 3);   // bijective: nwg % 8 == 0
    int tN = (swz % nxb) * 128;
    int tM = (swz / nxb) * 128;
    int l = tid & 63, w = tid >> 6;
    int wm = (w & 1) * 64, wn = (w >> 1) * 64;
    int lrow = l & 15, lgrp = l >> 4;

    f32x4 acc[4][4];
    #pragma unroll
    for (int mi = 0; mi < 4; ++mi)
        #pragma unroll
        for (int nj = 0; nj < 4; ++nj) acc[mi][nj] = (f32x4){0.f, 0.f, 0.f, 0.f};

    for (int k0 = 0; k0 < K; k0 += 64) {
        #pragma unroll
        for (int i = 0; i < 4; ++i) {
            int f = tid + 256 * i;          // 0..1023
            int r = f >> 3, g = f & 7;
            short8v sa = *(const short8v*)(A + (size_t)(tM + r) * lda + k0 + g * 8);
            const float* srcW = W + (size_t)(tN + r) * K + k0 + g * 8;
            float4 w0 = *(const float4*)srcW;
            float4 w1 = *(const float4*)(srcW + 4);
            short8v sw = { f2bf(w0.x), f2bf(w0.y), f2bf(w0.z), f2bf(w0.w),
                           f2bf(w1.x), f2bf(w1.y), f2bf(w1.z), f2bf(w1.w) };
            int dst = r * 64 + ((g ^ (r & 7)) * 8);
            *(short8v*)&As[dst] = sa;
            *(short8v*)&Bs[dst] = sw;
        }
        __syncthreads();
        #pragma unroll
        for (int kk = 0; kk < 2; ++kk) {
            short8v af[4], bfr[4];
            #pragma unroll
            for (int mi = 0; mi < 4; ++mi) {
                int row = wm + mi * 16 + lrow;
                int g = kk * 4 + lgrp;
                af[mi] = *(const short8v*)&As[row * 64 + ((g ^ (row & 7)) * 8)];
            }
            #pragma unroll
            for (int nj = 0; nj < 4; ++nj) {
                int row = wn + nj * 16 + lrow;
                int g = kk * 4 + lgrp;
                bfr[nj] = *(const short8v*)&Bs[row * 64 + ((g ^ (row & 7)) * 8)];
            }
            #pragma unroll
            for (int mi = 0; mi < 4; ++mi)
                #pragma unroll
                for (int nj = 0; nj < 4; ++nj)
                    acc[mi][nj] = __builtin_amdgcn_mfma_f32_16x16x32_bf16(af[mi], bfr[nj], acc[mi][nj], 0, 0, 0);
        }
        __syncthreads();
    }

    // C/D layout: col = lane&15, row = (lane>>4)*4 + e   [m89-verified]
    #pragma unroll
    for (int nj = 0; nj < 4; ++nj) {
        int oo = tN + wn + nj * 16 + lrow;
        float s = gg[oo] * rsqrtf(vv[oo] + 1e-5f);
        float d = bb[oo] - mm[oo] * s;
        #pragma unroll
        for (int mi = 0; mi < 4; ++mi) {
            int m0 = tM + wm + mi * 16 + lgrp * 4;
            float4 tv;
            float* tp = (float*)&tv;
            #pragma unroll
            for (int e = 0; e < 4; ++e) {
                float t = s * acc[mi][nj][e] + d;
                tp[e] = t >= 0.f ? t : 0.2f * t;
            }
            if constexpr (MODE == 0) {
                float* out = (float*)outp;
                #pragma unroll
                for (int e = 0; e < 4; ++e)
                    out[(size_t)(m0 + e) * ldo + oo] = tp[e];
            } else {
                short* out = (short*)outp;
                #pragma unroll
                for (int e = 0; e < 4; ++e)
                    out[(size_t)(m0 + e) * ldo + oo] = f2bf(tp[e]);
                if constexpr (MODE == 2) {
                    int b = m0 >> 12, n = m0 & (NPTS - 1);
                    *(float4*)&out2[((size_t)b * 1024 + oo) * NPTS + n] = tv;
                }
            }
        }
    }
}

// ---------------- fp32 tiled GEMM: bn_act: 1=BN+lrelu, 0=+bias, 2=raw ----------------
__global__ __launch_bounds__(256) void k_gemm(
    const float* __restrict__ A, int lda,
    const float* __restrict__ W,
    const float* __restrict__ gg, const float* __restrict__ bb,
    const float* __restrict__ mm, const float* __restrict__ vv,
    int bn_act,
    float* __restrict__ out, int ldo,
    int K, int O)
{
    __shared__ __align__(16) float As[16][68];
    __shared__ __align__(16) float Bs[16][68];
    int tid = threadIdx.x;
    int tM = blockIdx.x * 64;
    int tN = blockIdx.y * 64;
    int lk = tid & 15, lr = tid >> 4;
    float acc[4][4];
    #pragma unroll
    for (int i = 0; i < 4; ++i)
        #pragma unroll
        for (int j = 0; j < 4; ++j) acc[i][j] = 0.f;

    for (int k0 = 0; k0 < K; k0 += 16) {
        #pragma unroll
        for (int i = 0; i < 4; ++i) {
            int r = lr + 16 * i;
            As[lk][r] = A[(size_t)(tM + r) * lda + k0 + lk];
        }
        #pragma unroll
        for (int i = 0; i < 4; ++i) {
            int r = lr + 16 * i;
            int oo = tN + r;
            Bs[lk][r] = (oo < O) ? W[(size_t)oo * K + k0 + lk] : 0.f;
        }
        __syncthreads();
        #pragma unroll
        for (int kk = 0; kk < 16; ++kk) {
            float4 av = *(const float4*)&As[kk][lr * 4];
            float4 bv = *(const float4*)&Bs[kk][lk * 4];
            float a0 = av.x, a1 = av.y, a2 = av.z, a3 = av.w;
            float b0 = bv.x, b1 = bv.y, b2 = bv.z, b3 = bv.w;
            acc[0][0] += a0*b0; acc[0][1] += a0*b1; acc[0][2] += a0*b2; acc[0][3] += a0*b3;
            acc[1][0] += a1*b0; acc[1][1] += a1*b1; acc[1][2] += a1*b2; acc[1][3] += a1*b3;
            acc[2][0] += a2*b0; acc[2][1] += a2*b1; acc[2][2] += a2*b2; acc[2][3] += a2*b3;
            acc[3][0] += a3*b0; acc[3][1] += a3*b1; acc[3][2] += a3*b2; acc[3][3] += a3*b3;
        }
        __syncthreads();
    }
    int ty = lr, tx = lk;
    #pragma unroll
    for (int i = 0; i < 4; ++i) {
        int m = tM + ty * 4 + i;
        #pragma unroll
        for (int j = 0; j < 4; ++j) {
            int oo = tN + tx * 4 + j;
            if (oo < O) {
                float t = acc[i][j];
                if (bn_act == 1) {
                    float s = gg[oo] * rsqrtf(vv[oo] + 1e-5f);
                    float d = bb[oo] - mm[oo] * s;
                    t = s * t + d;
                    t = t >= 0.f ? t : 0.2f * t;
                } else if (bn_act == 0) {
                    t += bb[oo];
                }
                out[(size_t)m * ldo + oo] = t;
            }
        }
    }
}

extern "C" void kernel_launch(void* const* d_in, const int* in_sizes, int n_in,
                              void* d_out, int out_size, void* d_ws, size_t ws_size,
                              hipStream_t stream)
{
    const float* x = (const float*)d_in[0];
    const float* ew[4] = {(const float*)d_in[1],  (const float*)d_in[6],  (const float*)d_in[11], (const float*)d_in[16]};
    const float* eg[4] = {(const float*)d_in[2],  (const float*)d_in[7],  (const float*)d_in[12], (const float*)d_in[17]};
    const float* ebp[4]= {(const float*)d_in[3],  (const float*)d_in[8],  (const float*)d_in[13], (const float*)d_in[18]};
    const float* em[4] = {(const float*)d_in[4],  (const float*)d_in[9],  (const float*)d_in[14], (const float*)d_in[19]};
    const float* ev[4] = {(const float*)d_in[5],  (const float*)d_in[10], (const float*)d_in[15], (const float*)d_in[20]};
    const float* col_w = (const float*)d_in[21];
    const float* col_g = (const float*)d_in[22];
    const float* col_b = (const float*)d_in[23];
    const float* col_m = (const float*)d_in[24];
    const float* col_v = (const float*)d_in[25];
    const float* c5_w = (const float*)d_in[26]; const float* c5_g = (const float*)d_in[27];
    const float* c5_b = (const float*)d_in[28]; const float* c5_m = (const float*)d_in[29];
    const float* c5_v = (const float*)d_in[30];
    const float* c6_w = (const float*)d_in[31]; const float* c6_g = (const float*)d_in[32];
    const float* c6_b = (const float*)d_in[33]; const float* c6_m = (const float*)d_in[34];
    const float* c6_v = (const float*)d_in[35];
    const float* c7_w = (const float*)d_in[36]; const float* c7_g = (const float*)d_in[37];
    const float* c7_b = (const float*)d_in[38]; const float* c7_m = (const float*)d_in[39];
    const float* c7_v = (const float*)d_in[40];
    const float* c8_w = (const float*)d_in[41]; const float* c8_b = (const float*)d_in[42];

    // workspace layout (floats), total 26951680 floats = 107.8 MiB (< proven 126 MiB)
    // CORRECTED from round 11: idxb is B*N*20 = 327680 ints -> ends at 442368, nothing overlaps.
    float* ws    = (float*)d_ws;
    float* xyzT  = ws;                          // (B*N x 6)        [0, 98304)
    float* xx    = ws + 98304;                  // (B*N)            [98304, 114688)
    int*   idxb  = (int*)(ws + 114688);         // (B*N x 20)       [114688, 442368)
    float* wcbuf = ws + 442368;                 // up to 16384      [442368, 458752)
    float* qlists= ws + 458752;                 // (B*N x 4 x 20)   [458752, 1769472)
    int*   gcnt  = (int*)(ws + 1769472);        // (B*N)            [1769472, 1785856)
    float* gval  = ws + 1785856;                // (64 x B*N)       [1785856, 2834432)
    int*   gidx  = (int*)(ws + 2834432);        // (64 x B*N)       [2834432, 3883008)
    float* xcat  = ws + 3883008;                // (B*N x 192) fp32 [3883008, 7028736)
    float* x7    = ws + 7028736;                // (B*N x 256) fp32 [7028736, 11223040)  (gq alias)
    short* abuf  = (short*)(ws + 11223040);     // (B*N x 1408) bf16 [11223040, 22757376)
    short* x6b   = (short*)(ws + 22757376);     // (B*N x 512) bf16  [22757376, 26951680)
    float* gq    = x7;                          // GQ (B*N x up to 256), dead before c7

    float* out_logits = (float*)d_out;                               // (B,N,13)
    float* out_x5     = (float*)d_out + (size_t)NBATCH * NPTS * 13;  // (B,1024,N)
    // pd scratch: the x5 output region (dead until c5's MODE-2 epilogue, after all kNN)
    float* pd = out_x5;                         // [4096][4096] per batch

    dim3 blk(256);
    dim3 pd_grid(64, 64);
    dim3 sel_grid(128, 4);

    k_transpose_in<<<dim3(NTOT/256), blk, 0, stream>>>(x, xyzT);

    // ---- ec1: input xyz (C=3, stride 6) -> xcat col 0 + abuf col 0 ----
    k_row_norms<<<dim3(NTOT/256), blk, 0, stream>>>(xyzT, 6, 3, xx);
    hipMemsetAsync(gcnt, 0, NTOT * sizeof(int), stream);
    for (int b = 0; b < NBATCH; ++b) {
        k_pd_gemm<4><<<pd_grid, blk, 0, stream>>>(xyzT + (size_t)b * NPTS * 6, 6, xx + b * NPTS, pd);
        k_knn_select<<<sel_grid, blk, 0, stream>>>(pd, b, qlists);
        k_knn_collect<<<sel_grid, blk, 0, stream>>>(pd, b, qlists, gcnt, gval, gidx);
    }
    k_knn_final<<<dim3(NTOT/256), blk, 0, stream>>>(gcnt, gval, gidx, idxb);
    k_make_wc<<<dim3((2*64*3+255)/256), blk, 0, stream>>>(ew[0], wcbuf, 64, 3);
    k_gw_small<<<dim3(NTOT*128/256), blk, 0, stream>>>(xyzT, wcbuf, gq);
    k_edge_max<64,true><<<dim3(NTOT*64/256), blk, 0, stream>>>(gq, idxb,
        eg[0], ebp[0], em[0], ev[0], xcat + 0, 192, abuf + 0, 1408);

    // ---- ec2: x1 -> xcat col 64 + abuf col 64 ----
    k_row_norms<<<dim3(NTOT/256), blk, 0, stream>>>(xcat + 0, 192, 64, xx);
    hipMemsetAsync(gcnt, 0, NTOT * sizeof(int), stream);
    for (int b = 0; b < NBATCH; ++b) {
        k_pd_gemm<64><<<pd_grid, blk, 0, stream>>>(xcat + (size_t)b * NPTS * 192, 192, xx + b * NPTS, pd);
        k_knn_select<<<sel_grid, blk, 0, stream>>>(pd, b, qlists);
        k_knn_collect<<<sel_grid, blk, 0, stream>>>(pd, b, qlists, gcnt, gval, gidx);
    }
    k_knn_final<<<dim3(NTOT/256), blk, 0, stream>>>(gcnt, gval, gidx, idxb);
    k_make_wc<<<dim3((2*64*64+255)/256), blk, 0, stream>>>(ew[1], wcbuf, 64, 64);
    k_gemm<<<dim3(NTOT/64, 128/64), blk, 0, stream>>>(xcat + 0, 192, wcbuf,
        nullptr, nullptr, nullptr, nullptr, 2, gq, 128, 64, 128);
    k_edge_max<64,true><<<dim3(NTOT*64/256), blk, 0, stream>>>(gq, idxb,
        eg[1], ebp[1], em[1], ev[1], xcat + 64, 192, abuf + 64, 1408);

    // ---- ec3: x2 -> xcat col 128 + abuf col 128 ----
    k_row_norms<<<dim3(NTOT/256), blk, 0, stream>>>(xcat + 64, 192, 64, xx);
    hipMemsetAsync(gcnt, 0, NTOT * sizeof(int), stream);
    for (int b = 0; b < NBATCH; ++b) {
        k_pd_gemm<64><<<pd_grid, blk, 0, stream>>>(xcat + 64 + (size_t)b * NPTS * 192, 192, xx + b * NPTS, pd);
        k_knn_select<<<sel_grid, blk, 0, stream>>>(pd, b, qlists);
        k_knn_collect<<<sel_grid, blk, 0, stream>>>(pd, b, qlists, gcnt, gval, gidx);
    }
    k_knn_final<<<dim3(NTOT/256), blk, 0, stream>>>(gcnt, gval, gidx, idxb);
    k_make_wc<<<dim3((2*64*64+255)/256), blk, 0, stream>>>(ew[2], wcbuf, 64, 64);
    k_gemm<<<dim3(NTOT/64, 128/64), blk, 0, stream>>>(xcat + 64, 192, wcbuf,
        nullptr, nullptr, nullptr, nullptr, 2, gq, 128, 64, 128);
    k_edge_max<64,true><<<dim3(NTOT*64/256), blk, 0, stream>>>(gq, idxb,
        eg[2], ebp[2], em[2], ev[2], xcat + 128, 192, abuf + 128, 1408);

    // ---- ec4: x3 -> abuf cols 192..319 (O=128, bf16 only) ----
    k_row_norms<<<dim3(NTOT/256), blk, 0, stream>>>(xcat + 128, 192, 64, xx);
    hipMemsetAsync(gcnt, 0, NTOT * sizeof(int), stream);
    for (int b = 0; b < NBATCH; ++b) {
        k_pd_gemm<64><<<pd_grid, blk, 0, stream>>>(xcat + 128 + (size_t)b * NPTS * 192, 192, xx + b * NPTS, pd);
        k_knn_select<<<sel_grid, blk, 0, stream>>>(pd, b, qlists);
        k_knn_collect<<<sel_grid, blk, 0, stream>>>(pd, b, qlists, gcnt, gval, gidx);
    }
    k_knn_final<<<dim3(NTOT/256), blk, 0, stream>>>(gcnt, gval, gidx, idxb);
    k_make_wc<<<dim3((2*128*64+255)/256), blk, 0, stream>>>(ew[3], wcbuf, 128, 64);
    k_gemm<<<dim3(NTOT/64, 256/64), blk, 0, stream>>>(xcat + 128, 192, wcbuf,
        nullptr, nullptr, nullptr, nullptr, 2, gq, 256, 64, 256);
    k_edge_max<128,false><<<dim3(NTOT*128/256), blk, 0, stream>>>(gq, idxb,
        eg[3], ebp[3], em[3], ev[3], nullptr, 0, abuf + 192, 1408);

    // ---- color: rgb -> abuf cols 320..383 ----
    k_color<<<dim3(NTOT*64/256), blk, 0, stream>>>(xyzT, col_w, col_g, col_b, col_m, col_v,
        abuf + 320, 1408);

    // ---- c5: (384 -> 1024) bf16 MFMA; bf16 -> abuf cols 384+, fp32 transposed -> out_x5 ----
    k_gemm_mfma<2><<<dim3((1024/128) * (NTOT/128)), blk, 0, stream>>>(abuf, 1408, c5_w,
        c5_g, c5_b, c5_m, c5_v, abuf + 384, 1408, out_x5, 384, 1024);

    // ---- c6: (1408 -> 512) bf16 MFMA -> x6b bf16 ----
    k_gemm_mfma<1><<<dim3((512/128) * (NTOT/128)), blk, 0, stream>>>(abuf, 1408, c6_w,
        c6_g, c6_b, c6_m, c6_v, x6b, 512, nullptr, 1408, 512);

    // ---- c7: (512 -> 256) bf16 MFMA -> x7 fp32 ----
    k_gemm_mfma<0><<<dim3((256/128) * (NTOT/128)), blk, 0, stream>>>(x6b, 512, c7_w,
        c7_g, c7_b, c7_m, c7_v, x7, 256, nullptr, 512, 256);

    // ---- c8: (256 -> 13) + bias, straight into d_out (B,N,13) ----
    k_gemm<<<dim3(NTOT/64, 1), blk, 0, stream>>>(x7, 256, c8_w,
        nullptr, c8_b, nullptr, nullptr, 0, out_logits, 13, 256, 13);
}

// Round 13
// 1807.914 us; speedup vs baseline: 1.5572x; 1.0738x over previous
//
#include <hip/hip_runtime.h>
#include <math.h>

#define NPTS 4096
#define NBATCH 4
#define NTOT (NBATCH*NPTS)
#define KNN 20

typedef __attribute__((ext_vector_type(8))) short short8v;
typedef __attribute__((ext_vector_type(4))) float f32x4;

__device__ __forceinline__ float lrelu_f(float h) { return h >= 0.f ? h : 0.2f * h; }

// fp32 -> bf16 bits, round-to-nearest-even (finite inputs)
__device__ __forceinline__ short f2bf(float f) {
    unsigned u = __float_as_uint(f);
    u += 0x7fffu + ((u >> 16) & 1u);
    return (short)(u >> 16);
}

// ---------------- x:(B,6,N) -> xyzT:(B*N,6) ----------------
__global__ __launch_bounds__(256) void k_transpose_in(const float* __restrict__ x, float* __restrict__ xyzT)
{
    int p = blockIdx.x * 256 + threadIdx.x;
    if (p >= NTOT) return;
    int b = p >> 12, n = p & (NPTS - 1);
    #pragma unroll
    for (int c = 0; c < 6; ++c)
        xyzT[(size_t)p * 6 + c] = x[((size_t)b * 6 + c) * NPTS + n];
}

// ---------------- row squared norms ----------------
__global__ __launch_bounds__(256) void k_row_norms(const float* __restrict__ f, int stride, int C, float* __restrict__ xx)
{
    int p = blockIdx.x * 256 + threadIdx.x;
    if (p >= NTOT) return;
    const float* r = f + (size_t)p * stride;
    float s = 0.f;
    for (int c = 0; c < C; ++c) { float v = r[c]; s += v * v; }
    xx[p] = s;
}

// ---------------- fp32 -> bf16 weight conversion (once per layer set) ----------------
__global__ __launch_bounds__(256) void k_w2bf(const float* __restrict__ w, short* __restrict__ wb, int n)
{
    int i = blockIdx.x * 256 + threadIdx.x;
    if (i < n) wb[i] = f2bf(w[i]);
}

// ---------------- build combined edge weights: wc = [W1 ; W2-W1], (2O x C) ----------------
__global__ __launch_bounds__(256) void k_make_wc(
    const float* __restrict__ w,   // (O, 2C) row-major
    float* __restrict__ wc,        // (2O, C) row-major
    int O, int C)
{
    int e = blockIdx.x * 256 + threadIdx.x;
    if (e >= 2 * O * C) return;
    int j = e / C, c = e - j * C;
    if (j < O) {
        wc[e] = w[(size_t)j * 2 * C + c];
    } else {
        int o = j - O;
        wc[e] = w[(size_t)o * 2 * C + C + c] - w[(size_t)o * 2 * C + c];
    }
}

// ---------------- ec1 GQ: (NTOT,6) xyz x (128,3) wc -> (NTOT,128) ----------------
__global__ __launch_bounds__(256) void k_gw_small(
    const float* __restrict__ xyzT,
    const float* __restrict__ wc,
    float* __restrict__ GQ)
{
    int t = blockIdx.x * 256 + threadIdx.x;
    int p = t >> 7, j = t & 127;
    if (p >= NTOT) return;
    const float* f = xyzT + (size_t)p * 6;
    GQ[(size_t)p * 128 + j] = f[0]*wc[j*3+0] + f[1]*wc[j*3+1] + f[2]*wc[j*3+2];
}

// ---------------- edge max: out[p][o] = lrelu(s*(sel_k GQ[nbr_k][o] + GQ[p][O+o]) + d) ----
template<int O, bool FOUT>
__global__ __launch_bounds__(256) void k_edge_max(
    const float* __restrict__ GQ,      // (NTOT, 2O)
    const int* __restrict__ idx,       // (NTOT, 20) batch-local
    const float* __restrict__ gg, const float* __restrict__ bb,
    const float* __restrict__ mm, const float* __restrict__ vv,
    float* __restrict__ out, int ostride,
    short* __restrict__ aout, int aostride)
{
    int t = blockIdx.x * 256 + threadIdx.x;
    int p = t / O;
    int o = t - p * O;
    if (p >= NTOT) return;
    int b = p >> 12;
    const int* ip = idx + (size_t)p * KNN;
    float mx = -INFINITY, mn = INFINITY;
    #pragma unroll 5
    for (int k = 0; k < KNN; ++k) {
        int r = b * NPTS + ip[k];
        float v = GQ[(size_t)r * (2 * O) + o];
        mx = fmaxf(mx, v); mn = fminf(mn, v);
    }
    float s = gg[o] * rsqrtf(vv[o] + 1e-5f);
    float d = bb[o] - mm[o] * s;
    float q = GQ[(size_t)p * (2 * O) + O + o];
    float h = s * (((s >= 0.f) ? mx : mn) + q) + d;
    float res = lrelu_f(h);
    if constexpr (FOUT) out[(size_t)p * ostride + o] = res;
    aout[(size_t)p * aostride + o] = f2bf(res);
}

// ---------------- symmetric pd GEMM: dot matrix is symmetric, compute each 64x64 tile once ----
// pd[c][q] = 2*dot(c,q) - xx[c];  pd[q][c] = 2*dot(c,q) - xx[q]  (bit-identical to two passes:
// FMA is operand-commutative, same k-order). Triangular grid of 2080 blocks (bi <= bj).
#define PD_FMA_BLOCK \
    { \
        float4 av = *(const float4*)&As[kk][lr * 4]; \
        float4 bv = *(const float4*)&Bs[kk][lk * 4]; \
        float a0 = av.x, a1 = av.y, a2 = av.z, a3 = av.w; \
        float b0 = bv.x, b1 = bv.y, b2 = bv.z, b3 = bv.w; \
        acc[0][0] += a0*b0; acc[0][1] += a0*b1; acc[0][2] += a0*b2; acc[0][3] += a0*b3; \
        acc[1][0] += a1*b0; acc[1][1] += a1*b1; acc[1][2] += a1*b2; acc[1][3] += a1*b3; \
        acc[2][0] += a2*b0; acc[2][1] += a2*b1; acc[2][2] += a2*b2; acc[2][3] += a2*b3; \
        acc[3][0] += a3*b0; acc[3][1] += a3*b1; acc[3][2] += a3*b2; acc[3][3] += a3*b3; \
    }

template<int CK>  // 64 or 4 (C=3 zero-padded)
__global__ __launch_bounds__(256) void k_pd_gemm(
    const float* __restrict__ feat, int fstride,   // batch base (4096 rows)
    const float* __restrict__ xxb,                 // batch norms (4096)
    float* __restrict__ pd)                        // [4096][4096]
{
    __shared__ __align__(16) float As[16][68];
    __shared__ __align__(16) float Bs[16][68];
    int tid = threadIdx.x;
    // triangular decode: t -> (bi, bj), 0 <= bi <= bj < 64; offset(i) = i*(129-i)/2
    int t = blockIdx.x;
    int bi = (int)((129.0f - sqrtf(16641.0f - 8.0f * (float)t)) * 0.5f);
    bi = bi < 0 ? 0 : (bi > 63 ? 63 : bi);
    while (bi * (129 - bi) / 2 > t) --bi;
    while ((bi + 1) * (129 - (bi + 1)) / 2 <= t) ++bi;
    int bj = bi + (t - bi * (129 - bi) / 2);
    int tM = bi * 64;   // candidate rows
    int tN = bj * 64;   // query cols
    int lk = tid & 15, lr = tid >> 4;
    float acc[4][4];
    #pragma unroll
    for (int i = 0; i < 4; ++i)
        #pragma unroll
        for (int j = 0; j < 4; ++j) acc[i][j] = 0.f;

    if constexpr (CK == 64) {
        for (int k0 = 0; k0 < 64; k0 += 16) {
            #pragma unroll
            for (int i = 0; i < 4; ++i) {
                int r = lr + 16 * i;
                As[lk][r] = feat[(size_t)(tM + r) * fstride + k0 + lk];
                Bs[lk][r] = feat[(size_t)(tN + r) * fstride + k0 + lk];
            }
            __syncthreads();
            #pragma unroll
            for (int kk = 0; kk < 16; ++kk) PD_FMA_BLOCK
            __syncthreads();
        }
    } else {
        int r = tid >> 2, kk4 = tid & 3;
        As[kk4][r] = (kk4 < 3) ? feat[(size_t)(tM + r) * fstride + kk4] : 0.f;
        Bs[kk4][r] = (kk4 < 3) ? feat[(size_t)(tN + r) * fstride + kk4] : 0.f;
        __syncthreads();
        #pragma unroll
        for (int kk = 0; kk < 4; ++kk) PD_FMA_BLOCK
    }
    #pragma unroll
    for (int i = 0; i < 4; ++i) {
        int c = tM + lr * 4 + i;
        float xc = xxb[c];
        float4 v = make_float4(2.f*acc[i][0]-xc, 2.f*acc[i][1]-xc, 2.f*acc[i][2]-xc, 2.f*acc[i][3]-xc);
        *(float4*)&pd[(size_t)c * 4096 + tN + lk * 4] = v;
    }
    if (bi != bj) {
        #pragma unroll
        for (int j = 0; j < 4; ++j) {
            int q = tN + lk * 4 + j;
            float xq = xxb[q];
            float4 v = make_float4(2.f*acc[0][j]-xq, 2.f*acc[1][j]-xq, 2.f*acc[2][j]-xq, 2.f*acc[3][j]-xq);
            *(float4*)&pd[(size_t)q * 4096 + tM + lr * 4] = v;
        }
    }
}

// ---------------- kNN select: per (query, slice) top-20 VALUES via branchless min/max chain ----
__global__ __launch_bounds__(256) void k_knn_select(
    const float* __restrict__ pd, int b,
    float* __restrict__ qlists)
{
    __shared__ __align__(16) float sm[5120];     // stage 128*36=4608 | dump 256*20=5120
    float (*ds)[36] = (float(*)[36])sm;
    int tid = threadIdx.x;
    int q0 = blockIdx.x * 32;
    int schunk = blockIdx.y;
    int q = tid & 31, sl = tid >> 5;

    float lv[KNN];
    #pragma unroll
    for (int j = 0; j < KNN; ++j) lv[j] = -INFINITY;

    for (int t = 0; t < 8; ++t) {
        int c0 = schunk * 1024 + t * 128;
        __syncthreads();
        #pragma unroll
        for (int r = 0; r < 4; ++r) {
            int f = tid + 256 * r;
            int row = f >> 3, col4 = f & 7;
            *(float4*)&ds[row][col4 * 4] = *(const float4*)&pd[(size_t)(c0 + row) * 4096 + q0 + col4 * 4];
        }
        __syncthreads();
        #pragma unroll
        for (int i = 0; i < 16; ++i) {
            float cv = ds[sl * 16 + i][q];
            float prev = lv[0];
            lv[0] = fmaxf(lv[0], cv);
            #pragma unroll
            for (int j = 1; j < KNN; ++j) {
                float cur = lv[j];
                lv[j] = fminf(prev, fmaxf(cv, cur));
                prev = cur;
            }
        }
    }
    __syncthreads();
    #pragma unroll
    for (int j = 0; j < KNN; ++j) sm[tid * KNN + j] = lv[j];
    __syncthreads();
    if (tid < 32) {
        int hp[8] = {0,0,0,0,0,0,0,0};
        size_t obase = ((size_t)(b * 4096 + q0 + tid) * 4 + schunk) * KNN;
        #pragma unroll 1
        for (int r = 0; r < KNN; ++r) {
            float bv = -INFINITY; int bs = 0;
            #pragma unroll
            for (int s = 0; s < 8; ++s) {
                float v = sm[(s * 32 + tid) * KNN + hp[s]];
                if (v > bv) { bv = v; bs = s; }
            }
            qlists[obase + r] = bv;
            #pragma unroll
            for (int s = 0; s < 8; ++s) hp[s] += (bs == s);
        }
    }
}

// ---------------- kNN collect: v20 = global 20th value; append all cv >= v20 ----------------
__global__ __launch_bounds__(256) void k_knn_collect(
    const float* __restrict__ pd, int b,
    const float* __restrict__ qlists,
    int* __restrict__ gcnt,            // [NTOT]
    float* __restrict__ gval,          // [64][NTOT]
    int* __restrict__ gidx)            // [64][NTOT]
{
    __shared__ __align__(16) float sm[4608];
    __shared__ float v20s[32];
    float (*ds)[36] = (float(*)[36])sm;
    int tid = threadIdx.x;
    int q0 = blockIdx.x * 32;
    int schunk = blockIdx.y;

    if (tid < 32) {
        const float* ql = qlists + (size_t)(b * 4096 + q0 + tid) * 4 * KNN;
        int hp[4] = {0,0,0,0};
        float bv = -INFINITY;
        #pragma unroll 1
        for (int r = 0; r < KNN; ++r) {
            bv = -INFINITY; int bs = 0;
            #pragma unroll
            for (int s = 0; s < 4; ++s) {
                float v = ql[s * KNN + hp[s]];
                if (v > bv) { bv = v; bs = s; }
            }
            #pragma unroll
            for (int s = 0; s < 4; ++s) hp[s] += (bs == s);
        }
        v20s[tid] = bv;
    }
    __syncthreads();
    int q = tid & 31, sl = tid >> 5;
    float v20 = v20s[q];
    int gq = b * 4096 + q0 + q;

    for (int t = 0; t < 8; ++t) {
        int c0 = schunk * 1024 + t * 128;
        __syncthreads();
        #pragma unroll
        for (int r = 0; r < 4; ++r) {
            int f = tid + 256 * r;
            int row = f >> 3, col4 = f & 7;
            *(float4*)&ds[row][col4 * 4] = *(const float4*)&pd[(size_t)(c0 + row) * 4096 + q0 + col4 * 4];
        }
        __syncthreads();
        #pragma unroll
        for (int i = 0; i < 16; ++i) {
            float cv = ds[sl * 16 + i][q];
            if (cv >= v20) {
                int pos = atomicAdd(&gcnt[gq], 1);
                if (pos < 64) {
                    gval[(size_t)pos * NTOT + gq] = cv;
                    gidx[(size_t)pos * NTOT + gq] = c0 + sl * 16 + i;
                }
            }
        }
    }
}

// ---------------- kNN final: sort survivors by (val desc, idx asc), emit top-20 indices ------
// Also zeroes gcnt for the next layer (replaces per-layer memset).
__global__ __launch_bounds__(256) void k_knn_final(
    int* __restrict__ gcnt,
    const float* __restrict__ gval,
    const int* __restrict__ gidx,
    int* __restrict__ idx_out)
{
    int gq = blockIdx.x * 256 + threadIdx.x;
    if (gq >= NTOT) return;
    int n = gcnt[gq]; n = n > 64 ? 64 : n;
    gcnt[gq] = 0;
    float lv[KNN]; int li[KNN];
    #pragma unroll
    for (int j = 0; j < KNN; ++j) { lv[j] = -INFINITY; li[j] = 0x7fffffff; }
    for (int e = 0; e < n; ++e) {
        float cv = gval[(size_t)e * NTOT + gq];
        int  ci = gidx[(size_t)e * NTOT + gq];
        #pragma unroll
        for (int j = 0; j < KNN; ++j) {
            bool sw = (cv > lv[j]) || (cv == lv[j] && ci < li[j]);
            float tf = lv[j]; int ti = li[j];
            lv[j] = sw ? cv : lv[j];  li[j] = sw ? ci : li[j];
            cv    = sw ? tf : cv;     ci    = sw ? ti : ci;
        }
    }
    #pragma unroll
    for (int j = 0; j < KNN; ++j) idx_out[(size_t)gq * KNN + j] = li[j];
}

// ---------------- color MLP (3 -> 64), bf16 out only ----------------
__global__ __launch_bounds__(256) void k_color(
    const float* __restrict__ xyzT,
    const float* __restrict__ w,
    const float* __restrict__ gg, const float* __restrict__ bb,
    const float* __restrict__ mm, const float* __restrict__ vv,
    short* __restrict__ aout, int aostride)
{
    int t = blockIdx.x * 256 + threadIdx.x;
    int p = t >> 6, o = t & 63;
    if (p >= NTOT) return;
    const float* rgb = xyzT + (size_t)p * 6 + 3;
    float h = rgb[0] * w[o*3+0] + rgb[1] * w[o*3+1] + rgb[2] * w[o*3+2];
    float s = gg[o] * rsqrtf(vv[o] + 1e-5f);
    float d = bb[o] - mm[o] * s;
    aout[(size_t)p * aostride + o] = f2bf(lrelu_f(s * h + d));
}

// ---------------- bf16 MFMA GEMM: out[m][o] = lrelu(BN( A[m][:] . W[o][:] )) ----------------
// A bf16 (M x K row-major, lda in shorts), W bf16 (O x K, pre-converted). 128x128 tile,
// 4 waves, BK=64, XOR-swizzled LDS. Flat grid, bijective XCD swizzle (nwg%8==0).
// MODE 0: fp32 out. MODE 1: bf16 out. MODE 2: bf16 out + fp32 transposed out2 (c5 -> x5).
template<int MODE>
__global__ __launch_bounds__(256) void k_gemm_mfma(
    const short* __restrict__ A, int lda,
    const short* __restrict__ W,
    const float* __restrict__ gg, const float* __restrict__ bb,
    const float* __restrict__ mm, const float* __restrict__ vv,
    void* __restrict__ outp, int ldo,
    float* __restrict__ out2,
    int K, int O)
{
    __shared__ short As[128 * 64];
    __shared__ short Bs[128 * 64];
    int tid = threadIdx.x;
    int nxb = O >> 7;
    int nwg = nxb * (NTOT / 128);
    int bid = blockIdx.x;
    int swz = (bid & 7) * (nwg >> 3) + (bid >> 3);   // bijective: nwg % 8 == 0
    int tN = (swz % nxb) * 128;
    int tM = (swz / nxb) * 128;
    int l = tid & 63, w = tid >> 6;
    int wm = (w & 1) * 64, wn = (w >> 1) * 64;
    int lrow = l & 15, lgrp = l >> 4;

    f32x4 acc[4][4];
    #pragma unroll
    for (int mi = 0; mi < 4; ++mi)
        #pragma unroll
        for (int nj = 0; nj < 4; ++nj) acc[mi][nj] = (f32x4){0.f, 0.f, 0.f, 0.f};

    for (int k0 = 0; k0 < K; k0 += 64) {
        #pragma unroll
        for (int i = 0; i < 4; ++i) {
            int f = tid + 256 * i;          // 0..1023
            int r = f >> 3, g = f & 7;
            short8v sa = *(const short8v*)(A + (size_t)(tM + r) * lda + k0 + g * 8);
            short8v sw = *(const short8v*)(W + (size_t)(tN + r) * K + k0 + g * 8);
            int dst = r * 64 + ((g ^ (r & 7)) * 8);
            *(short8v*)&As[dst] = sa;
            *(short8v*)&Bs[dst] = sw;
        }
        __syncthreads();
        #pragma unroll
        for (int kk = 0; kk < 2; ++kk) {
            short8v af[4], bfr[4];
            #pragma unroll
            for (int mi = 0; mi < 4; ++mi) {
                int row = wm + mi * 16 + lrow;
                int g = kk * 4 + lgrp;
                af[mi] = *(const short8v*)&As[row * 64 + ((g ^ (row & 7)) * 8)];
            }
            #pragma unroll
            for (int nj = 0; nj < 4; ++nj) {
                int row = wn + nj * 16 + lrow;
                int g = kk * 4 + lgrp;
                bfr[nj] = *(const short8v*)&Bs[row * 64 + ((g ^ (row & 7)) * 8)];
            }
            #pragma unroll
            for (int mi = 0; mi < 4; ++mi)
                #pragma unroll
                for (int nj = 0; nj < 4; ++nj)
                    acc[mi][nj] = __builtin_amdgcn_mfma_f32_16x16x32_bf16(af[mi], bfr[nj], acc[mi][nj], 0, 0, 0);
        }
        __syncthreads();
    }

    // C/D layout: col = lane&15, row = (lane>>4)*4 + e   [m89-verified]
    #pragma unroll
    for (int nj = 0; nj < 4; ++nj) {
        int oo = tN + wn + nj * 16 + lrow;
        float s = gg[oo] * rsqrtf(vv[oo] + 1e-5f);
        float d = bb[oo] - mm[oo] * s;
        #pragma unroll
        for (int mi = 0; mi < 4; ++mi) {
            int m0 = tM + wm + mi * 16 + lgrp * 4;
            float4 tv;
            float* tp = (float*)&tv;
            #pragma unroll
            for (int e = 0; e < 4; ++e) {
                float t = s * acc[mi][nj][e] + d;
                tp[e] = t >= 0.f ? t : 0.2f * t;
            }
            if constexpr (MODE == 0) {
                float* out = (float*)outp;
                #pragma unroll
                for (int e = 0; e < 4; ++e)
                    out[(size_t)(m0 + e) * ldo + oo] = tp[e];
            } else {
                short* out = (short*)outp;
                #pragma unroll
                for (int e = 0; e < 4; ++e)
                    out[(size_t)(m0 + e) * ldo + oo] = f2bf(tp[e]);
                if constexpr (MODE == 2) {
                    int b = m0 >> 12, n = m0 & (NPTS - 1);
                    *(float4*)&out2[((size_t)b * 1024 + oo) * NPTS + n] = tv;
                }
            }
        }
    }
}

// ---------------- fp32 tiled GEMM: bn_act: 1=BN+lrelu, 0=+bias, 2=raw ----------------
__global__ __launch_bounds__(256) void k_gemm(
    const float* __restrict__ A, int lda,
    const float* __restrict__ W,
    const float* __restrict__ gg, const float* __restrict__ bb,
    const float* __restrict__ mm, const float* __restrict__ vv,
    int bn_act,
    float* __restrict__ out, int ldo,
    int K, int O)
{
    __shared__ __align__(16) float As[16][68];
    __shared__ __align__(16) float Bs[16][68];
    int tid = threadIdx.x;
    int tM = blockIdx.x * 64;
    int tN = blockIdx.y * 64;
    int lk = tid & 15, lr = tid >> 4;
    float acc[4][4];
    #pragma unroll
    for (int i = 0; i < 4; ++i)
        #pragma unroll
        for (int j = 0; j < 4; ++j) acc[i][j] = 0.f;

    for (int k0 = 0; k0 < K; k0 += 16) {
        #pragma unroll
        for (int i = 0; i < 4; ++i) {
            int r = lr + 16 * i;
            As[lk][r] = A[(size_t)(tM + r) * lda + k0 + lk];
        }
        #pragma unroll
        for (int i = 0; i < 4; ++i) {
            int r = lr + 16 * i;
            int oo = tN + r;
            Bs[lk][r] = (oo < O) ? W[(size_t)oo * K + k0 + lk] : 0.f;
        }
        __syncthreads();
        #pragma unroll
        for (int kk = 0; kk < 16; ++kk) {
            float4 av = *(const float4*)&As[kk][lr * 4];
            float4 bv = *(const float4*)&Bs[kk][lk * 4];
            float a0 = av.x, a1 = av.y, a2 = av.z, a3 = av.w;
            float b0 = bv.x, b1 = bv.y, b2 = bv.z, b3 = bv.w;
            acc[0][0] += a0*b0; acc[0][1] += a0*b1; acc[0][2] += a0*b2; acc[0][3] += a0*b3;
            acc[1][0] += a1*b0; acc[1][1] += a1*b1; acc[1][2] += a1*b2; acc[1][3] += a1*b3;
            acc[2][0] += a2*b0; acc[2][1] += a2*b1; acc[2][2] += a2*b2; acc[2][3] += a2*b3;
            acc[3][0] += a3*b0; acc[3][1] += a3*b1; acc[3][2] += a3*b2; acc[3][3] += a3*b3;
        }
        __syncthreads();
    }
    int ty = lr, tx = lk;
    #pragma unroll
    for (int i = 0; i < 4; ++i) {
        int m = tM + ty * 4 + i;
        #pragma unroll
        for (int j = 0; j < 4; ++j) {
            int oo = tN + tx * 4 + j;
            if (oo < O) {
                float t = acc[i][j];
                if (bn_act == 1) {
                    float s = gg[oo] * rsqrtf(vv[oo] + 1e-5f);
                    float d = bb[oo] - mm[oo] * s;
                    t = s * t + d;
                    t = t >= 0.f ? t : 0.2f * t;
                } else if (bn_act == 0) {
                    t += bb[oo];
                }
                out[(size_t)m * ldo + oo] = t;
            }
        }
    }
}

extern "C" void kernel_launch(void* const* d_in, const int* in_sizes, int n_in,
                              void* d_out, int out_size, void* d_ws, size_t ws_size,
                              hipStream_t stream)
{
    const float* x = (const float*)d_in[0];
    const float* ew[4] = {(const float*)d_in[1],  (const float*)d_in[6],  (const float*)d_in[11], (const float*)d_in[16]};
    const float* eg[4] = {(const float*)d_in[2],  (const float*)d_in[7],  (const float*)d_in[12], (const float*)d_in[17]};
    const float* ebp[4]= {(const float*)d_in[3],  (const float*)d_in[8],  (const float*)d_in[13], (const float*)d_in[18]};
    const float* em[4] = {(const float*)d_in[4],  (const float*)d_in[9],  (const float*)d_in[14], (const float*)d_in[19]};
    const float* ev[4] = {(const float*)d_in[5],  (const float*)d_in[10], (const float*)d_in[15], (const float*)d_in[20]};
    const float* col_w = (const float*)d_in[21];
    const float* col_g = (const float*)d_in[22];
    const float* col_b = (const float*)d_in[23];
    const float* col_m = (const float*)d_in[24];
    const float* col_v = (const float*)d_in[25];
    const float* c5_w = (const float*)d_in[26]; const float* c5_g = (const float*)d_in[27];
    const float* c5_b = (const float*)d_in[28]; const float* c5_m = (const float*)d_in[29];
    const float* c5_v = (const float*)d_in[30];
    const float* c6_w = (const float*)d_in[31]; const float* c6_g = (const float*)d_in[32];
    const float* c6_b = (const float*)d_in[33]; const float* c6_m = (const float*)d_in[34];
    const float* c6_v = (const float*)d_in[35];
    const float* c7_w = (const float*)d_in[36]; const float* c7_g = (const float*)d_in[37];
    const float* c7_b = (const float*)d_in[38]; const float* c7_m = (const float*)d_in[39];
    const float* c7_v = (const float*)d_in[40];
    const float* c8_w = (const float*)d_in[41]; const float* c8_b = (const float*)d_in[42];

    // workspace layout (floats), total 27574272 floats = 110.3 MiB (< proven 126 MiB)
    float* ws    = (float*)d_ws;
    float* xyzT  = ws;                          // (B*N x 6)        [0, 98304)
    float* xx    = ws + 98304;                  // (B*N)            [98304, 114688)
    int*   idxb  = (int*)(ws + 114688);         // (B*N x 20)       [114688, 442368)
    float* wcbuf = ws + 442368;                 // up to 16384      [442368, 458752)
    float* qlists= ws + 458752;                 // (B*N x 4 x 20)   [458752, 1769472)
    int*   gcnt  = (int*)(ws + 1769472);        // (B*N)            [1769472, 1785856)
    float* gval  = ws + 1785856;                // (64 x B*N)       [1785856, 2834432)
    int*   gidx  = (int*)(ws + 2834432);        // (64 x B*N)       [2834432, 3883008)
    float* xcat  = ws + 3883008;                // (B*N x 192) fp32 [3883008, 7028736)
    float* x7    = ws + 7028736;                // (B*N x 256) fp32 [7028736, 11223040)  (gq alias)
    short* abuf  = (short*)(ws + 11223040);     // (B*N x 1408) bf16 [11223040, 22757376)
    short* x6b   = (short*)(ws + 22757376);     // (B*N x 512) bf16  [22757376, 26951680)
    short* wb5   = (short*)(ws + 26951680);     // 1024x384 bf16     [26951680, 27148288)
    short* wb6   = (short*)(ws + 27148288);     // 512x1408 bf16     [27148288, 27508736)
    short* wb7   = (short*)(ws + 27508736);     // 256x512 bf16      [27508736, 27574272)
    float* gq    = x7;                          // GQ (B*N x up to 256), dead before c7

    float* out_logits = (float*)d_out;                               // (B,N,13)
    float* out_x5     = (float*)d_out + (size_t)NBATCH * NPTS * 13;  // (B,1024,N)
    // pd scratch: the x5 output region (dead until c5's MODE-2 epilogue, after all kNN)
    float* pd = out_x5;                         // [4096][4096] per batch

    dim3 blk(256);
    dim3 pd_grid(2080);                          // triangular 64x64-tile grid
    dim3 sel_grid(128, 4);

    k_transpose_in<<<dim3(NTOT/256), blk, 0, stream>>>(x, xyzT);
    k_w2bf<<<dim3((1024*384+255)/256), blk, 0, stream>>>(c5_w, wb5, 1024*384);
    k_w2bf<<<dim3((512*1408+255)/256), blk, 0, stream>>>(c6_w, wb6, 512*1408);
    k_w2bf<<<dim3((256*512+255)/256), blk, 0, stream>>>(c7_w, wb7, 256*512);
    hipMemsetAsync(gcnt, 0, NTOT * sizeof(int), stream);   // k_knn_final re-zeroes per layer

    // ---- ec1: input xyz (C=3, stride 6) -> xcat col 0 + abuf col 0 ----
    k_row_norms<<<dim3(NTOT/256), blk, 0, stream>>>(xyzT, 6, 3, xx);
    for (int b = 0; b < NBATCH; ++b) {
        k_pd_gemm<4><<<pd_grid, blk, 0, stream>>>(xyzT + (size_t)b * NPTS * 6, 6, xx + b * NPTS, pd);
        k_knn_select<<<sel_grid, blk, 0, stream>>>(pd, b, qlists);
        k_knn_collect<<<sel_grid, blk, 0, stream>>>(pd, b, qlists, gcnt, gval, gidx);
    }
    k_knn_final<<<dim3(NTOT/256), blk, 0, stream>>>(gcnt, gval, gidx, idxb);
    k_make_wc<<<dim3((2*64*3+255)/256), blk, 0, stream>>>(ew[0], wcbuf, 64, 3);
    k_gw_small<<<dim3(NTOT*128/256), blk, 0, stream>>>(xyzT, wcbuf, gq);
    k_edge_max<64,true><<<dim3(NTOT*64/256), blk, 0, stream>>>(gq, idxb,
        eg[0], ebp[0], em[0], ev[0], xcat + 0, 192, abuf + 0, 1408);

    // ---- ec2: x1 -> xcat col 64 + abuf col 64 ----
    k_row_norms<<<dim3(NTOT/256), blk, 0, stream>>>(xcat + 0, 192, 64, xx);
    for (int b = 0; b < NBATCH; ++b) {
        k_pd_gemm<64><<<pd_grid, blk, 0, stream>>>(xcat + (size_t)b * NPTS * 192, 192, xx + b * NPTS, pd);
        k_knn_select<<<sel_grid, blk, 0, stream>>>(pd, b, qlists);
        k_knn_collect<<<sel_grid, blk, 0, stream>>>(pd, b, qlists, gcnt, gval, gidx);
    }
    k_knn_final<<<dim3(NTOT/256), blk, 0, stream>>>(gcnt, gval, gidx, idxb);
    k_make_wc<<<dim3((2*64*64+255)/256), blk, 0, stream>>>(ew[1], wcbuf, 64, 64);
    k_gemm<<<dim3(NTOT/64, 128/64), blk, 0, stream>>>(xcat + 0, 192, wcbuf,
        nullptr, nullptr, nullptr, nullptr, 2, gq, 128, 64, 128);
    k_edge_max<64,true><<<dim3(NTOT*64/256), blk, 0, stream>>>(gq, idxb,
        eg[1], ebp[1], em[1], ev[1], xcat + 64, 192, abuf + 64, 1408);

    // ---- ec3: x2 -> xcat col 128 + abuf col 128 ----
    k_row_norms<<<dim3(NTOT/256), blk, 0, stream>>>(xcat + 64, 192, 64, xx);
    for (int b = 0; b < NBATCH; ++b) {
        k_pd_gemm<64><<<pd_grid, blk, 0, stream>>>(xcat + 64 + (size_t)b * NPTS * 192, 192, xx + b * NPTS, pd);
        k_knn_select<<<sel_grid, blk, 0, stream>>>(pd, b, qlists);
        k_knn_collect<<<sel_grid, blk, 0, stream>>>(pd, b, qlists, gcnt, gval, gidx);
    }
    k_knn_final<<<dim3(NTOT/256), blk, 0, stream>>>(gcnt, gval, gidx, idxb);
    k_make_wc<<<dim3((2*64*64+255)/256), blk, 0, stream>>>(ew[2], wcbuf, 64, 64);
    k_gemm<<<dim3(NTOT/64, 128/64), blk, 0, stream>>>(xcat + 64, 192, wcbuf,
        nullptr, nullptr, nullptr, nullptr, 2, gq, 128, 64, 128);
    k_edge_max<64,true><<<dim3(NTOT*64/256), blk, 0, stream>>>(gq, idxb,
        eg[2], ebp[2], em[2], ev[2], xcat + 128, 192, abuf + 128, 1408);

    // ---- ec4: x3 -> abuf cols 192..319 (O=128, bf16 only) ----
    k_row_norms<<<dim3(NTOT/256), blk, 0, stream>>>(xcat + 128, 192, 64, xx);
    for (int b = 0; b < NBATCH; ++b) {
        k_pd_gemm<64><<<pd_grid, blk, 0, stream>>>(xcat + 128 + (size_t)b * NPTS * 192, 192, xx + b * NPTS, pd);
        k_knn_select<<<sel_grid, blk, 0, stream>>>(pd, b, qlists);
        k_knn_collect<<<sel_grid, blk, 0, stream>>>(pd, b, qlists, gcnt, gval, gidx);
    }
    k_knn_final<<<dim3(NTOT/256), blk, 0, stream>>>(gcnt, gval, gidx, idxb);
    k_make_wc<<<dim3((2*128*64+255)/256), blk, 0, stream>>>(ew[3], wcbuf, 128, 64);
    k_gemm<<<dim3(NTOT/64, 256/64), blk, 0, stream>>>(xcat + 128, 192, wcbuf,
        nullptr, nullptr, nullptr, nullptr, 2, gq, 256, 64, 256);
    k_edge_max<128,false><<<dim3(NTOT*128/256), blk, 0, stream>>>(gq, idxb,
        eg[3], ebp[3], em[3], ev[3], nullptr, 0, abuf + 192, 1408);

    // ---- color: rgb -> abuf cols 320..383 ----
    k_color<<<dim3(NTOT*64/256), blk, 0, stream>>>(xyzT, col_w, col_g, col_b, col_m, col_v,
        abuf + 320, 1408);

    // ---- c5: (384 -> 1024) bf16 MFMA; bf16 -> abuf cols 384+, fp32 transposed -> out_x5 ----
    k_gemm_mfma<2><<<dim3((1024/128) * (NTOT/128)), blk, 0, stream>>>(abuf, 1408, wb5,
        c5_g, c5_b, c5_m, c5_v, abuf + 384, 1408, out_x5, 384, 1024);

    // ---- c6: (1408 -> 512) bf16 MFMA -> x6b bf16 ----
    k_gemm_mfma<1><<<dim3((512/128) * (NTOT/128)), blk, 0, stream>>>(abuf, 1408, wb6,
        c6_g, c6_b, c6_m, c6_v, x6b, 512, nullptr, 1408, 512);

    // ---- c7: (512 -> 256) bf16 MFMA -> x7 fp32 ----
    k_gemm_mfma<0><<<dim3((256/128) * (NTOT/128)), blk, 0, stream>>>(x6b, 512, wb7,
        c7_g, c7_b, c7_m, c7_v, x7, 256, nullptr, 512, 256);

    // ---- c8: (256 -> 13) + bias, straight into d_out (B,N,13) ----
    k_gemm<<<dim3(NTOT/64, 1), blk, 0, stream>>>(x7, 256, c8_w,
        nullptr, c8_b, nullptr, nullptr, 0, out_logits, 13, 256, 13);
}

// Round 14
// 1395.565 us; speedup vs baseline: 2.0174x; 1.2955x over previous
//
#include <hip/hip_runtime.h>
#include <math.h>

#define NPTS 4096
#define NBATCH 4
#define NTOT (NBATCH*NPTS)
#define KNN 20

typedef __attribute__((ext_vector_type(8))) short short8v;
typedef __attribute__((ext_vector_type(4))) float f32x4;

__device__ __forceinline__ float lrelu_f(float h) { return h >= 0.f ? h : 0.2f * h; }

// fp32 -> bf16 bits, round-to-nearest-even (finite inputs)
__device__ __forceinline__ short f2bf(float f) {
    unsigned u = __float_as_uint(f);
    u += 0x7fffu + ((u >> 16) & 1u);
    return (short)(u >> 16);
}

// ---------------- x:(B,6,N) -> xyzT:(B*N,6) ----------------
__global__ __launch_bounds__(256) void k_transpose_in(const float* __restrict__ x, float* __restrict__ xyzT)
{
    int p = blockIdx.x * 256 + threadIdx.x;
    if (p >= NTOT) return;
    int b = p >> 12, n = p & (NPTS - 1);
    #pragma unroll
    for (int c = 0; c < 6; ++c)
        xyzT[(size_t)p * 6 + c] = x[((size_t)b * 6 + c) * NPTS + n];
}

// ---------------- row squared norms ----------------
__global__ __launch_bounds__(256) void k_row_norms(const float* __restrict__ f, int stride, int C, float* __restrict__ xx)
{
    int p = blockIdx.x * 256 + threadIdx.x;
    if (p >= NTOT) return;
    const float* r = f + (size_t)p * stride;
    float s = 0.f;
    for (int c = 0; c < C; ++c) { float v = r[c]; s += v * v; }
    xx[p] = s;
}

// ---------------- fp32 -> bf16 weight conversion (once per layer set) ----------------
__global__ __launch_bounds__(256) void k_w2bf(const float* __restrict__ w, short* __restrict__ wb, int n)
{
    int i = blockIdx.x * 256 + threadIdx.x;
    if (i < n) wb[i] = f2bf(w[i]);
}

// ---------------- build combined edge weights: wc = [W1 ; W2-W1], (2O x C) ----------------
__global__ __launch_bounds__(256) void k_make_wc(
    const float* __restrict__ w,   // (O, 2C) row-major
    float* __restrict__ wc,        // (2O, C) row-major
    int O, int C)
{
    int e = blockIdx.x * 256 + threadIdx.x;
    if (e >= 2 * O * C) return;
    int j = e / C, c = e - j * C;
    if (j < O) {
        wc[e] = w[(size_t)j * 2 * C + c];
    } else {
        int o = j - O;
        wc[e] = w[(size_t)o * 2 * C + C + c] - w[(size_t)o * 2 * C + c];
    }
}

// ---------------- ec1 GQ: (NTOT,6) xyz x (128,3) wc -> (NTOT,128) ----------------
__global__ __launch_bounds__(256) void k_gw_small(
    const float* __restrict__ xyzT,
    const float* __restrict__ wc,
    float* __restrict__ GQ)
{
    int t = blockIdx.x * 256 + threadIdx.x;
    int p = t >> 7, j = t & 127;
    if (p >= NTOT) return;
    const float* f = xyzT + (size_t)p * 6;
    GQ[(size_t)p * 128 + j] = f[0]*wc[j*3+0] + f[1]*wc[j*3+1] + f[2]*wc[j*3+2];
}

// ---------------- edge max: out[p][o] = lrelu(s*(sel_k GQ[nbr_k][o] + GQ[p][O+o]) + d) ----
template<int O, bool FOUT>
__global__ __launch_bounds__(256) void k_edge_max(
    const float* __restrict__ GQ,      // (NTOT, 2O)
    const int* __restrict__ idx,       // (NTOT, 20) batch-local
    const float* __restrict__ gg, const float* __restrict__ bb,
    const float* __restrict__ mm, const float* __restrict__ vv,
    float* __restrict__ out, int ostride,
    short* __restrict__ aout, int aostride)
{
    int t = blockIdx.x * 256 + threadIdx.x;
    int p = t / O;
    int o = t - p * O;
    if (p >= NTOT) return;
    int b = p >> 12;
    const int* ip = idx + (size_t)p * KNN;
    float mx = -INFINITY, mn = INFINITY;
    #pragma unroll 5
    for (int k = 0; k < KNN; ++k) {
        int r = b * NPTS + ip[k];
        float v = GQ[(size_t)r * (2 * O) + o];
        mx = fmaxf(mx, v); mn = fminf(mn, v);
    }
    float s = gg[o] * rsqrtf(vv[o] + 1e-5f);
    float d = bb[o] - mm[o] * s;
    float q = GQ[(size_t)p * (2 * O) + O + o];
    float h = s * (((s >= 0.f) ? mx : mn) + q) + d;
    float res = lrelu_f(h);
    if constexpr (FOUT) out[(size_t)p * ostride + o] = res;
    aout[(size_t)p * aostride + o] = f2bf(res);
}

// ---------------- symmetric pd GEMM, QUERY-MAJOR output ----------------
// pd[q][c] = 2*dot(q,c) - xx[c].  Tile (bi,bj): rows R=bi-range, cols C=bj-range,
// acc[i][j] = dot(R_i, C_j). Writes pd[R_i][C_j] = 2acc - xx[C_j] and (bi!=bj)
// pd[C_j][R_i] = 2acc - xx[R_i]. Bit-identical dot values to previous rounds.
#define PD_FMA_BLOCK \
    { \
        float4 av = *(const float4*)&As[kk][lr * 4]; \
        float4 bv = *(const float4*)&Bs[kk][lk * 4]; \
        float a0 = av.x, a1 = av.y, a2 = av.z, a3 = av.w; \
        float b0 = bv.x, b1 = bv.y, b2 = bv.z, b3 = bv.w; \
        acc[0][0] += a0*b0; acc[0][1] += a0*b1; acc[0][2] += a0*b2; acc[0][3] += a0*b3; \
        acc[1][0] += a1*b0; acc[1][1] += a1*b1; acc[1][2] += a1*b2; acc[1][3] += a1*b3; \
        acc[2][0] += a2*b0; acc[2][1] += a2*b1; acc[2][2] += a2*b2; acc[2][3] += a2*b3; \
        acc[3][0] += a3*b0; acc[3][1] += a3*b1; acc[3][2] += a3*b2; acc[3][3] += a3*b3; \
    }

template<int CK>  // 64 or 4 (C=3 zero-padded)
__global__ __launch_bounds__(256) void k_pd_gemm(
    const float* __restrict__ feat, int fstride,   // batch base (4096 rows)
    const float* __restrict__ xxb,                 // batch norms (4096)
    float* __restrict__ pd)                        // [4096 q][4096 c]
{
    __shared__ __align__(16) float As[16][68];
    __shared__ __align__(16) float Bs[16][68];
    int tid = threadIdx.x;
    // triangular decode: t -> (bi, bj), 0 <= bi <= bj < 64
    int t = blockIdx.x;
    int bi = (int)((129.0f - sqrtf(16641.0f - 8.0f * (float)t)) * 0.5f);
    bi = bi < 0 ? 0 : (bi > 63 ? 63 : bi);
    while (bi * (129 - bi) / 2 > t) --bi;
    while ((bi + 1) * (129 - (bi + 1)) / 2 <= t) ++bi;
    int bj = bi + (t - bi * (129 - bi) / 2);
    int tM = bi * 64;
    int tN = bj * 64;
    int lk = tid & 15, lr = tid >> 4;
    float acc[4][4];
    #pragma unroll
    for (int i = 0; i < 4; ++i)
        #pragma unroll
        for (int j = 0; j < 4; ++j) acc[i][j] = 0.f;

    if constexpr (CK == 64) {
        for (int k0 = 0; k0 < 64; k0 += 16) {
            #pragma unroll
            for (int i = 0; i < 4; ++i) {
                int r = lr + 16 * i;
                As[lk][r] = feat[(size_t)(tM + r) * fstride + k0 + lk];
                Bs[lk][r] = feat[(size_t)(tN + r) * fstride + k0 + lk];
            }
            __syncthreads();
            #pragma unroll
            for (int kk = 0; kk < 16; ++kk) PD_FMA_BLOCK
            __syncthreads();
        }
    } else {
        int r = tid >> 2, kk4 = tid & 3;
        As[kk4][r] = (kk4 < 3) ? feat[(size_t)(tM + r) * fstride + kk4] : 0.f;
        Bs[kk4][r] = (kk4 < 3) ? feat[(size_t)(tN + r) * fstride + kk4] : 0.f;
        __syncthreads();
        #pragma unroll
        for (int kk = 0; kk < 4; ++kk) PD_FMA_BLOCK
    }
    // query-major writes
    float4 xxC = *(const float4*)&xxb[tN + lk * 4];
    const float* xc = (const float*)&xxC;
    #pragma unroll
    for (int i = 0; i < 4; ++i) {
        int q = tM + lr * 4 + i;
        float4 v = make_float4(2.f*acc[i][0]-xc[0], 2.f*acc[i][1]-xc[1],
                               2.f*acc[i][2]-xc[2], 2.f*acc[i][3]-xc[3]);
        *(float4*)&pd[(size_t)q * 4096 + tN + lk * 4] = v;
    }
    if (bi != bj) {
        float4 xxR = *(const float4*)&xxb[tM + lr * 4];
        const float* xr = (const float*)&xxR;
        #pragma unroll
        for (int j = 0; j < 4; ++j) {
            int q = tN + lk * 4 + j;
            float4 v = make_float4(2.f*acc[0][j]-xr[0], 2.f*acc[1][j]-xr[1],
                                   2.f*acc[2][j]-xr[2], 2.f*acc[3][j]-xr[3]);
            *(float4*)&pd[(size_t)q * 4096 + tM + lr * 4] = v;
        }
    }
}

// ---------------- fused kNN select+collect+final: one block = 8 queries x all 4096 cands ---
// Stages 8 pd rows (128 KB) in LDS once. Pass 1: dual branchless top-20 value chains per lane;
// wave bitonic merge (all 64 lanes = one query) -> exact v20. Pass 2: collect survivors from
// LDS; rank by (val desc, idx asc) via shuffles -> exact jax.lax.top_k indices.
__global__ __launch_bounds__(512) void k_knn_sc(
    const float* __restrict__ pd, int b,
    int* __restrict__ idx_out)
{
    __shared__ __align__(16) float sd[8 * 4096];   // 128 KB
    __shared__ int   scnt[8];
    __shared__ float sval[8][64];
    __shared__ int   sidx[8][64];
    int tid = threadIdx.x;
    int q0 = blockIdx.x * 8;

    #pragma unroll
    for (int it = 0; it < 16; ++it) {
        int f = tid + 512 * it;              // 0..8191 float4s
        int row = f >> 10, c4 = f & 1023;
        *(float4*)&sd[row * 4096 + c4 * 4] =
            *(const float4*)&pd[(size_t)(q0 + row) * 4096 + c4 * 4];
    }
    if (tid < 8) scnt[tid] = 0;
    __syncthreads();

    int w = tid >> 6, lane = tid & 63;
    const float* rowp = &sd[w * 4096];

    // ---- pass 1: two independent 20-chains (ILP) over this lane's 64 cands ----
    float lvA[KNN], lvB[KNN];
    #pragma unroll
    for (int j = 0; j < KNN; ++j) { lvA[j] = -INFINITY; lvB[j] = -INFINITY; }
    #pragma unroll
    for (int i = 0; i < 8; ++i) {
        float4 ca = *(const float4*)&rowp[i * 256 + lane * 4];
        float4 cb = *(const float4*)&rowp[(i + 8) * 256 + lane * 4];
        const float* cap = (const float*)&ca;
        const float* cbp = (const float*)&cb;
        #pragma unroll
        for (int e = 0; e < 4; ++e) {
            float cva = cap[e], cvb = cbp[e];
            float pa = lvA[0], pb = lvB[0];
            lvA[0] = fmaxf(lvA[0], cva);
            lvB[0] = fmaxf(lvB[0], cvb);
            #pragma unroll
            for (int j = 1; j < KNN; ++j) {
                float ua = lvA[j], ub = lvB[j];
                lvA[j] = fminf(pa, fmaxf(cva, ua));
                lvB[j] = fminf(pb, fmaxf(cvb, ub));
                pa = ua; pb = ub;
            }
        }
    }
    // ---- local merge A+B into sorted-desc m[32] (top-32 with -inf pads) ----
    float m[32];
    #pragma unroll
    for (int j = 0; j < 32; ++j) {
        float a = (j < KNN) ? lvA[j] : -INFINITY;
        float bb2 = (31 - j < KNN) ? lvB[31 - j] : -INFINITY;
        m[j] = fmaxf(a, bb2);
    }
    #pragma unroll
    for (int s = 16; s >= 1; s >>= 1) {
        #pragma unroll
        for (int j = 0; j < 32; ++j) {
            if ((j & s) == 0) {
                float a = m[j], c = m[j | s];
                m[j] = fmaxf(a, c); m[j | s] = fminf(a, c);
            }
        }
    }
    // ---- wave bitonic top-32 merge: 6 xor rounds, all lanes end with global list ----
    #pragma unroll
    for (int d = 1; d < 64; d <<= 1) {
        float r[32];
        #pragma unroll
        for (int j = 0; j < 32; ++j) r[j] = __shfl_xor(m[31 - j], d);
        #pragma unroll
        for (int j = 0; j < 32; ++j) m[j] = fmaxf(m[j], r[j]);
        #pragma unroll
        for (int s = 16; s >= 1; s >>= 1) {
            #pragma unroll
            for (int j = 0; j < 32; ++j) {
                if ((j & s) == 0) {
                    float a = m[j], c = m[j | s];
                    m[j] = fmaxf(a, c); m[j | s] = fminf(a, c);
                }
            }
        }
    }
    float v20 = m[19];

    // ---- pass 2: collect survivors (cv >= v20) from LDS ----
    #pragma unroll 4
    for (int i = 0; i < 16; ++i) {
        float4 c4v = *(const float4*)&rowp[i * 256 + lane * 4];
        const float* cp = (const float*)&c4v;
        #pragma unroll
        for (int e = 0; e < 4; ++e) {
            if (cp[e] >= v20) {
                int pos = atomicAdd(&scnt[w], 1);
                if (pos < 64) {
                    sval[w][pos] = cp[e];
                    sidx[w][pos] = i * 256 + lane * 4 + e;
                }
            }
        }
    }
    __syncthreads();

    // ---- rank (val desc, idx asc) via shuffle broadcast; emit top-20 ----
    int n = scnt[w] > 64 ? 64 : scnt[w];
    float myv = (lane < n) ? sval[w][lane] : -INFINITY;
    int   myi = (lane < n) ? sidx[w][lane] : 0x7fffffff;
    int rank = 0;
    for (int k = 0; k < 64; ++k) {
        float ov = __shfl(myv, k);
        int   oi = __shfl(myi, k);
        rank += ((ov > myv) || (ov == myv && oi < myi)) ? 1 : 0;
    }
    if (lane < n && rank < KNN)
        idx_out[(size_t)(b * 4096 + q0 + w) * KNN + rank] = myi;
}

// ---------------- color MLP (3 -> 64), bf16 out only ----------------
__global__ __launch_bounds__(256) void k_color(
    const float* __restrict__ xyzT,
    const float* __restrict__ w,
    const float* __restrict__ gg, const float* __restrict__ bb,
    const float* __restrict__ mm, const float* __restrict__ vv,
    short* __restrict__ aout, int aostride)
{
    int t = blockIdx.x * 256 + threadIdx.x;
    int p = t >> 6, o = t & 63;
    if (p >= NTOT) return;
    const float* rgb = xyzT + (size_t)p * 6 + 3;
    float h = rgb[0] * w[o*3+0] + rgb[1] * w[o*3+1] + rgb[2] * w[o*3+2];
    float s = gg[o] * rsqrtf(vv[o] + 1e-5f);
    float d = bb[o] - mm[o] * s;
    aout[(size_t)p * aostride + o] = f2bf(lrelu_f(s * h + d));
}

// ---------------- bf16 MFMA GEMM (unchanged from round 13) ----------------
template<int MODE>
__global__ __launch_bounds__(256) void k_gemm_mfma(
    const short* __restrict__ A, int lda,
    const short* __restrict__ W,
    const float* __restrict__ gg, const float* __restrict__ bb,
    const float* __restrict__ mm, const float* __restrict__ vv,
    void* __restrict__ outp, int ldo,
    float* __restrict__ out2,
    int K, int O)
{
    __shared__ short As[128 * 64];
    __shared__ short Bs[128 * 64];
    int tid = threadIdx.x;
    int nxb = O >> 7;
    int nwg = nxb * (NTOT / 128);
    int bid = blockIdx.x;
    int swz = (bid & 7) * (nwg >> 3) + (bid >> 3);   // bijective: nwg % 8 == 0
    int tN = (swz % nxb) * 128;
    int tM = (swz / nxb) * 128;
    int l = tid & 63, w = tid >> 6;
    int wm = (w & 1) * 64, wn = (w >> 1) * 64;
    int lrow = l & 15, lgrp = l >> 4;

    f32x4 acc[4][4];
    #pragma unroll
    for (int mi = 0; mi < 4; ++mi)
        #pragma unroll
        for (int nj = 0; nj < 4; ++nj) acc[mi][nj] = (f32x4){0.f, 0.f, 0.f, 0.f};

    for (int k0 = 0; k0 < K; k0 += 64) {
        #pragma unroll
        for (int i = 0; i < 4; ++i) {
            int f = tid + 256 * i;
            int r = f >> 3, g = f & 7;
            short8v sa = *(const short8v*)(A + (size_t)(tM + r) * lda + k0 + g * 8);
            short8v sw = *(const short8v*)(W + (size_t)(tN + r) * K + k0 + g * 8);
            int dst = r * 64 + ((g ^ (r & 7)) * 8);
            *(short8v*)&As[dst] = sa;
            *(short8v*)&Bs[dst] = sw;
        }
        __syncthreads();
        #pragma unroll
        for (int kk = 0; kk < 2; ++kk) {
            short8v af[4], bfr[4];
            #pragma unroll
            for (int mi = 0; mi < 4; ++mi) {
                int row = wm + mi * 16 + lrow;
                int g = kk * 4 + lgrp;
                af[mi] = *(const short8v*)&As[row * 64 + ((g ^ (row & 7)) * 8)];
            }
            #pragma unroll
            for (int nj = 0; nj < 4; ++nj) {
                int row = wn + nj * 16 + lrow;
                int g = kk * 4 + lgrp;
                bfr[nj] = *(const short8v*)&Bs[row * 64 + ((g ^ (row & 7)) * 8)];
            }
            #pragma unroll
            for (int mi = 0; mi < 4; ++mi)
                #pragma unroll
                for (int nj = 0; nj < 4; ++nj)
                    acc[mi][nj] = __builtin_amdgcn_mfma_f32_16x16x32_bf16(af[mi], bfr[nj], acc[mi][nj], 0, 0, 0);
        }
        __syncthreads();
    }

    #pragma unroll
    for (int nj = 0; nj < 4; ++nj) {
        int oo = tN + wn + nj * 16 + lrow;
        float s = gg[oo] * rsqrtf(vv[oo] + 1e-5f);
        float d = bb[oo] - mm[oo] * s;
        #pragma unroll
        for (int mi = 0; mi < 4; ++mi) {
            int m0 = tM + wm + mi * 16 + lgrp * 4;
            float4 tv;
            float* tp = (float*)&tv;
            #pragma unroll
            for (int e = 0; e < 4; ++e) {
                float t = s * acc[mi][nj][e] + d;
                tp[e] = t >= 0.f ? t : 0.2f * t;
            }
            if constexpr (MODE == 0) {
                float* out = (float*)outp;
                #pragma unroll
                for (int e = 0; e < 4; ++e)
                    out[(size_t)(m0 + e) * ldo + oo] = tp[e];
            } else {
                short* out = (short*)outp;
                #pragma unroll
                for (int e = 0; e < 4; ++e)
                    out[(size_t)(m0 + e) * ldo + oo] = f2bf(tp[e]);
                if constexpr (MODE == 2) {
                    int b = m0 >> 12, n = m0 & (NPTS - 1);
                    *(float4*)&out2[((size_t)b * 1024 + oo) * NPTS + n] = tv;
                }
            }
        }
    }
}

// ---------------- fp32 tiled GEMM: bn_act: 1=BN+lrelu, 0=+bias, 2=raw ----------------
__global__ __launch_bounds__(256) void k_gemm(
    const float* __restrict__ A, int lda,
    const float* __restrict__ W,
    const float* __restrict__ gg, const float* __restrict__ bb,
    const float* __restrict__ mm, const float* __restrict__ vv,
    int bn_act,
    float* __restrict__ out, int ldo,
    int K, int O)
{
    __shared__ __align__(16) float As[16][68];
    __shared__ __align__(16) float Bs[16][68];
    int tid = threadIdx.x;
    int tM = blockIdx.x * 64;
    int tN = blockIdx.y * 64;
    int lk = tid & 15, lr = tid >> 4;
    float acc[4][4];
    #pragma unroll
    for (int i = 0; i < 4; ++i)
        #pragma unroll
        for (int j = 0; j < 4; ++j) acc[i][j] = 0.f;

    for (int k0 = 0; k0 < K; k0 += 16) {
        #pragma unroll
        for (int i = 0; i < 4; ++i) {
            int r = lr + 16 * i;
            As[lk][r] = A[(size_t)(tM + r) * lda + k0 + lk];
        }
        #pragma unroll
        for (int i = 0; i < 4; ++i) {
            int r = lr + 16 * i;
            int oo = tN + r;
            Bs[lk][r] = (oo < O) ? W[(size_t)oo * K + k0 + lk] : 0.f;
        }
        __syncthreads();
        #pragma unroll
        for (int kk = 0; kk < 16; ++kk) {
            float4 av = *(const float4*)&As[kk][lr * 4];
            float4 bv = *(const float4*)&Bs[kk][lk * 4];
            float a0 = av.x, a1 = av.y, a2 = av.z, a3 = av.w;
            float b0 = bv.x, b1 = bv.y, b2 = bv.z, b3 = bv.w;
            acc[0][0] += a0*b0; acc[0][1] += a0*b1; acc[0][2] += a0*b2; acc[0][3] += a0*b3;
            acc[1][0] += a1*b0; acc[1][1] += a1*b1; acc[1][2] += a1*b2; acc[1][3] += a1*b3;
            acc[2][0] += a2*b0; acc[2][1] += a2*b1; acc[2][2] += a2*b2; acc[2][3] += a2*b3;
            acc[3][0] += a3*b0; acc[3][1] += a3*b1; acc[3][2] += a3*b2; acc[3][3] += a3*b3;
        }
        __syncthreads();
    }
    int ty = lr, tx = lk;
    #pragma unroll
    for (int i = 0; i < 4; ++i) {
        int m = tM + ty * 4 + i;
        #pragma unroll
        for (int j = 0; j < 4; ++j) {
            int oo = tN + tx * 4 + j;
            if (oo < O) {
                float t = acc[i][j];
                if (bn_act == 1) {
                    float s = gg[oo] * rsqrtf(vv[oo] + 1e-5f);
                    float d = bb[oo] - mm[oo] * s;
                    t = s * t + d;
                    t = t >= 0.f ? t : 0.2f * t;
                } else if (bn_act == 0) {
                    t += bb[oo];
                }
                out[(size_t)m * ldo + oo] = t;
            }
        }
    }
}

extern "C" void kernel_launch(void* const* d_in, const int* in_sizes, int n_in,
                              void* d_out, int out_size, void* d_ws, size_t ws_size,
                              hipStream_t stream)
{
    const float* x = (const float*)d_in[0];
    const float* ew[4] = {(const float*)d_in[1],  (const float*)d_in[6],  (const float*)d_in[11], (const float*)d_in[16]};
    const float* eg[4] = {(const float*)d_in[2],  (const float*)d_in[7],  (const float*)d_in[12], (const float*)d_in[17]};
    const float* ebp[4]= {(const float*)d_in[3],  (const float*)d_in[8],  (const float*)d_in[13], (const float*)d_in[18]};
    const float* em[4] = {(const float*)d_in[4],  (const float*)d_in[9],  (const float*)d_in[14], (const float*)d_in[19]};
    const float* ev[4] = {(const float*)d_in[5],  (const float*)d_in[10], (const float*)d_in[15], (const float*)d_in[20]};
    const float* col_w = (const float*)d_in[21];
    const float* col_g = (const float*)d_in[22];
    const float* col_b = (const float*)d_in[23];
    const float* col_m = (const float*)d_in[24];
    const float* col_v = (const float*)d_in[25];
    const float* c5_w = (const float*)d_in[26]; const float* c5_g = (const float*)d_in[27];
    const float* c5_b = (const float*)d_in[28]; const float* c5_m = (const float*)d_in[29];
    const float* c5_v = (const float*)d_in[30];
    const float* c6_w = (const float*)d_in[31]; const float* c6_g = (const float*)d_in[32];
    const float* c6_b = (const float*)d_in[33]; const float* c6_m = (const float*)d_in[34];
    const float* c6_v = (const float*)d_in[35];
    const float* c7_w = (const float*)d_in[36]; const float* c7_g = (const float*)d_in[37];
    const float* c7_b = (const float*)d_in[38]; const float* c7_m = (const float*)d_in[39];
    const float* c7_v = (const float*)d_in[40];
    const float* c8_w = (const float*)d_in[41]; const float* c8_b = (const float*)d_in[42];

    // workspace layout (floats), max offset 27574272 = 110.3 MiB (< proven 126 MiB)
    float* ws    = (float*)d_ws;
    float* xyzT  = ws;                          // (B*N x 6)        [0, 98304)
    float* xx    = ws + 98304;                  // (B*N)            [98304, 114688)
    int*   idxb  = (int*)(ws + 114688);         // (B*N x 20)       [114688, 442368)
    float* wcbuf = ws + 442368;                 // up to 16384      [442368, 458752)
    // [458752, 3883008) free (old qlists/gcnt/gval/gidx, no longer used)
    float* xcat  = ws + 3883008;                // (B*N x 192) fp32 [3883008, 7028736)
    float* x7    = ws + 7028736;                // (B*N x 256) fp32 [7028736, 11223040)  (gq alias)
    short* abuf  = (short*)(ws + 11223040);     // (B*N x 1408) bf16 [11223040, 22757376)
    short* x6b   = (short*)(ws + 22757376);     // (B*N x 512) bf16  [22757376, 26951680)
    short* wb5   = (short*)(ws + 26951680);     // 1024x384 bf16     [26951680, 27148288)
    short* wb6   = (short*)(ws + 27148288);     // 512x1408 bf16     [27148288, 27508736)
    short* wb7   = (short*)(ws + 27508736);     // 256x512 bf16      [27508736, 27574272)
    float* gq    = x7;                          // GQ (B*N x up to 256), dead before c7

    float* out_logits = (float*)d_out;                               // (B,N,13)
    float* out_x5     = (float*)d_out + (size_t)NBATCH * NPTS * 13;  // (B,1024,N)
    // pd scratch: the x5 output region (dead until c5's MODE-2 epilogue, after all kNN)
    float* pd = out_x5;                         // [4096 q][4096 c] per batch

    dim3 blk(256);
    dim3 pd_grid(2080);                          // triangular 64x64-tile grid
    dim3 sc_grid(512);                           // 8 queries per block
    dim3 sc_blk(512);

    k_transpose_in<<<dim3(NTOT/256), blk, 0, stream>>>(x, xyzT);
    k_w2bf<<<dim3((1024*384+255)/256), blk, 0, stream>>>(c5_w, wb5, 1024*384);
    k_w2bf<<<dim3((512*1408+255)/256), blk, 0, stream>>>(c6_w, wb6, 512*1408);
    k_w2bf<<<dim3((256*512+255)/256), blk, 0, stream>>>(c7_w, wb7, 256*512);

    // ---- ec1: input xyz (C=3, stride 6) -> xcat col 0 + abuf col 0 ----
    k_row_norms<<<dim3(NTOT/256), blk, 0, stream>>>(xyzT, 6, 3, xx);
    for (int b = 0; b < NBATCH; ++b) {
        k_pd_gemm<4><<<pd_grid, blk, 0, stream>>>(xyzT + (size_t)b * NPTS * 6, 6, xx + b * NPTS, pd);
        k_knn_sc<<<sc_grid, sc_blk, 0, stream>>>(pd, b, idxb);
    }
    k_make_wc<<<dim3((2*64*3+255)/256), blk, 0, stream>>>(ew[0], wcbuf, 64, 3);
    k_gw_small<<<dim3(NTOT*128/256), blk, 0, stream>>>(xyzT, wcbuf, gq);
    k_edge_max<64,true><<<dim3(NTOT*64/256), blk, 0, stream>>>(gq, idxb,
        eg[0], ebp[0], em[0], ev[0], xcat + 0, 192, abuf + 0, 1408);

    // ---- ec2: x1 -> xcat col 64 + abuf col 64 ----
    k_row_norms<<<dim3(NTOT/256), blk, 0, stream>>>(xcat + 0, 192, 64, xx);
    for (int b = 0; b < NBATCH; ++b) {
        k_pd_gemm<64><<<pd_grid, blk, 0, stream>>>(xcat + (size_t)b * NPTS * 192, 192, xx + b * NPTS, pd);
        k_knn_sc<<<sc_grid, sc_blk, 0, stream>>>(pd, b, idxb);
    }
    k_make_wc<<<dim3((2*64*64+255)/256), blk, 0, stream>>>(ew[1], wcbuf, 64, 64);
    k_gemm<<<dim3(NTOT/64, 128/64), blk, 0, stream>>>(xcat + 0, 192, wcbuf,
        nullptr, nullptr, nullptr, nullptr, 2, gq, 128, 64, 128);
    k_edge_max<64,true><<<dim3(NTOT*64/256), blk, 0, stream>>>(gq, idxb,
        eg[1], ebp[1], em[1], ev[1], xcat + 64, 192, abuf + 64, 1408);

    // ---- ec3: x2 -> xcat col 128 + abuf col 128 ----
    k_row_norms<<<dim3(NTOT/256), blk, 0, stream>>>(xcat + 64, 192, 64, xx);
    for (int b = 0; b < NBATCH; ++b) {
        k_pd_gemm<64><<<pd_grid, blk, 0, stream>>>(xcat + 64 + (size_t)b * NPTS * 192, 192, xx + b * NPTS, pd);
        k_knn_sc<<<sc_grid, sc_blk, 0, stream>>>(pd, b, idxb);
    }
    k_make_wc<<<dim3((2*64*64+255)/256), blk, 0, stream>>>(ew[2], wcbuf, 64, 64);
    k_gemm<<<dim3(NTOT/64, 128/64), blk, 0, stream>>>(xcat + 64, 192, wcbuf,
        nullptr, nullptr, nullptr, nullptr, 2, gq, 128, 64, 128);
    k_edge_max<64,true><<<dim3(NTOT*64/256), blk, 0, stream>>>(gq, idxb,
        eg[2], ebp[2], em[2], ev[2], xcat + 128, 192, abuf + 128, 1408);

    // ---- ec4: x3 -> abuf cols 192..319 (O=128, bf16 only) ----
    k_row_norms<<<dim3(NTOT/256), blk, 0, stream>>>(xcat + 128, 192, 64, xx);
    for (int b = 0; b < NBATCH; ++b) {
        k_pd_gemm<64><<<pd_grid, blk, 0, stream>>>(xcat + 128 + (size_t)b * NPTS * 192, 192, xx + b * NPTS, pd);
        k_knn_sc<<<sc_grid, sc_blk, 0, stream>>>(pd, b, idxb);
    }
    k_make_wc<<<dim3((2*128*64+255)/256), blk, 0, stream>>>(ew[3], wcbuf, 128, 64);
    k_gemm<<<dim3(NTOT/64, 256/64), blk, 0, stream>>>(xcat + 128, 192, wcbuf,
        nullptr, nullptr, nullptr, nullptr, 2, gq, 256, 64, 256);
    k_edge_max<128,false><<<dim3(NTOT*128/256), blk, 0, stream>>>(gq, idxb,
        eg[3], ebp[3], em[3], ev[3], nullptr, 0, abuf + 192, 1408);

    // ---- color: rgb -> abuf cols 320..383 ----
    k_color<<<dim3(NTOT*64/256), blk, 0, stream>>>(xyzT, col_w, col_g, col_b, col_m, col_v,
        abuf + 320, 1408);

    // ---- c5: (384 -> 1024) bf16 MFMA; bf16 -> abuf cols 384+, fp32 transposed -> out_x5 ----
    k_gemm_mfma<2><<<dim3((1024/128) * (NTOT/128)), blk, 0, stream>>>(abuf, 1408, wb5,
        c5_g, c5_b, c5_m, c5_v, abuf + 384, 1408, out_x5, 384, 1024);

    // ---- c6: (1408 -> 512) bf16 MFMA -> x6b bf16 ----
    k_gemm_mfma<1><<<dim3((512/128) * (NTOT/128)), blk, 0, stream>>>(abuf, 1408, wb6,
        c6_g, c6_b, c6_m, c6_v, x6b, 512, nullptr, 1408, 512);

    // ---- c7: (512 -> 256) bf16 MFMA -> x7 fp32 ----
    k_gemm_mfma<0><<<dim3((256/128) * (NTOT/128)), blk, 0, stream>>>(x6b, 512, wb7,
        c7_g, c7_b, c7_m, c7_v, x7, 256, nullptr, 512, 256);

    // ---- c8: (256 -> 13) + bias, straight into d_out (B,N,13) ----
    k_gemm<<<dim3(NTOT/64, 1), blk, 0, stream>>>(x7, 256, c8_w,
        nullptr, c8_b, nullptr, nullptr, 0, out_logits, 13, 256, 13);
}